// Round 1
// baseline (681.474 us; speedup 1.0000x reference)
//
#include <hip/hip_runtime.h>
#include <math.h>

// Problem constants (B, T1, T2, D) from the reference.
constexpr int BB = 8, T1 = 2048, T2 = 2048, D = 256;
constexpr int BM = 32;           // rows per block
constexpr int BN = 256;          // j-columns per tile
constexpr int KC = 32;           // k chunk staged in LDS
constexpr int ASTRIDE = D + 4;   // 260 floats: pad -> 2-way LDS conflicts (free)
constexpr int BSTRIDE = KC + 4;  // 36 floats: keeps float4 alignment, 4-way worst
constexpr float MARGIN = 1e-3f;  // fp32 dot error ~3e-5; 30x safety for flagging

// K1: fused fp32 score + per-row top-2 argmax + one-hot/gather epilogue.
__global__ __launch_bounds__(256, 2) void k_score_argmax(
    const float* __restrict__ s1, const float* __restrict__ s2,
    float* __restrict__ u, float* __restrict__ oh,
    int* __restrict__ qcount, int* __restrict__ queue, int qcap)
{
    __shared__ float As[BM * ASTRIDE];   // 33280 B
    __shared__ float Bs[BN * BSTRIDE];   // 36864 B
    __shared__ int   idx_s[BM];

    const int bx = blockIdx.x;
    const int b  = bx >> 6;              // 64 row-tiles per batch
    const int rt = bx & 63;
    const int r0 = rt * BM;
    const float* s1b = s1 + ((size_t)b * T1 + r0) * D;
    const float* s2b = s2 + (size_t)b * T2 * D;

    const int t  = threadIdx.x;
    const int tx = t & 31;               // column group (32 groups)
    const int ty = t >> 5;               // row group (8 groups x 4 rows)

    // Load A strip (32 x 256 floats) once, coalesced float4.
#pragma unroll
    for (int i = 0; i < 8; ++i) {
        int flat = i * 256 + t;          // float4 index, 2048 total
        int row = flat >> 6, k4 = flat & 63;
        float4 v = *(const float4*)(s1b + row * D + k4 * 4);
        *(float4*)(&As[row * ASTRIDE + k4 * 4]) = v;
    }

    float v1[4], v2[4]; int i1[4];
#pragma unroll
    for (int r = 0; r < 4; ++r) { v1[r] = -INFINITY; v2[r] = -INFINITY; i1[r] = 0; }

    for (int jt = 0; jt < T2 / BN; ++jt) {
        float acc[4][8];
#pragma unroll
        for (int r = 0; r < 4; ++r)
#pragma unroll
            for (int c = 0; c < 8; ++c) acc[r][c] = 0.f;

        for (int kc = 0; kc < D / KC; ++kc) {
            __syncthreads();             // protect Bs (and As on first pass)
#pragma unroll
            for (int i = 0; i < 8; ++i) {
                int flat = i * 256 + t;  // 2048 float4 = 256 rows x 8 float4
                int jrow = flat >> 3, k4 = flat & 7;
                float4 v = *(const float4*)(s2b + (size_t)(jt * BN + jrow) * D + kc * KC + k4 * 4);
                *(float4*)(&Bs[jrow * BSTRIDE + k4 * 4]) = v;
            }
            __syncthreads();
#pragma unroll
            for (int g = 0; g < KC / 4; ++g) {
                float4 a[4], bv[8];
#pragma unroll
                for (int r = 0; r < 4; ++r)
                    a[r] = *(const float4*)(&As[(ty * 4 + r) * ASTRIDE + kc * KC + g * 4]);
#pragma unroll
                for (int c = 0; c < 8; ++c)
                    bv[c] = *(const float4*)(&Bs[(tx + 32 * c) * BSTRIDE + g * 4]);
#pragma unroll
                for (int r = 0; r < 4; ++r)
#pragma unroll
                    for (int c = 0; c < 8; ++c) {
                        // strictly sequential k accumulation per score
                        acc[r][c] = fmaf(a[r].x, bv[c].x, acc[r][c]);
                        acc[r][c] = fmaf(a[r].y, bv[c].y, acc[r][c]);
                        acc[r][c] = fmaf(a[r].z, bv[c].z, acc[r][c]);
                        acc[r][c] = fmaf(a[r].w, bv[c].w, acc[r][c]);
                    }
            }
        }
        // Update running top-2 per row; j ascending within thread -> first-index ties kept.
#pragma unroll
        for (int r = 0; r < 4; ++r)
#pragma unroll
            for (int c = 0; c < 8; ++c) {
                float v = acc[r][c];
                int j = jt * BN + tx + 32 * c;
                if (v > v1[r])      { v2[r] = v1[r]; v1[r] = v; i1[r] = j; }
                else if (v > v2[r]) { v2[r] = v; }
            }
    }

    // Reduce top-2 across the 32 tx lanes (butterfly, width 32).
#pragma unroll
    for (int r = 0; r < 4; ++r) {
        float a1 = v1[r], a2 = v2[r]; int ai = i1[r];
#pragma unroll
        for (int off = 1; off < 32; off <<= 1) {
            float b1 = __shfl_xor(a1, off, 32);
            int   bi = __shfl_xor(ai, off, 32);
            float b2 = __shfl_xor(a2, off, 32);
            if (b1 > a1 || (b1 == a1 && bi < ai)) { a2 = fmaxf(a1, b2); a1 = b1; ai = bi; }
            else                                   { a2 = fmaxf(b1, a2); }
        }
        if (tx == 0) {
            int row = ty * 4 + r;
            idx_s[row] = ai;
            // Near-tie: defer to exact f64 fixup kernel.
            if (qcap > 0 && (a1 - a2) < MARGIN) {
                int pos = atomicAdd(qcount, 1);
                if (pos < qcap) queue[pos] = b * T1 + r0 + row;
            }
        }
    }
    __syncthreads();

    // u_tile: 32 rows x 64 float4, coalesced (each 64-lane group reads one s2 row).
    float* ub = u + ((size_t)b * T1 + r0) * D;
#pragma unroll
    for (int i = 0; i < 8; ++i) {
        int flat = i * 256 + t;
        int row = flat >> 6, f4 = flat & 63;
        float4 v = *(const float4*)(s2b + (size_t)idx_s[row] * D + f4 * 4);
        *(float4*)(ub + (size_t)row * D + f4 * 4) = v;
    }
    // one-hot: 32 rows x 512 float4, coalesced streaming stores.
    float* ohb = oh + ((size_t)b * T1 + r0) * T2;
#pragma unroll 4
    for (int i = 0; i < 64; ++i) {
        int flat = i * 256 + t;
        int row = flat >> 9, f4 = flat & 511;
        int base = f4 * 4;
        int id = idx_s[row];
        float4 v;
        v.x = (base     == id) ? 1.f : 0.f;
        v.y = (base + 1 == id) ? 1.f : 0.f;
        v.z = (base + 2 == id) ? 1.f : 0.f;
        v.w = (base + 3 == id) ? 1.f : 0.f;
        *(float4*)(ohb + (size_t)row * T2 + base) = v;
    }
}

// K2: exact float64 recompute for flagged (near-tie) rows; rewrites their outputs.
__global__ __launch_bounds__(256) void k_fixup(
    const float* __restrict__ s1, const float* __restrict__ s2,
    float* __restrict__ u, float* __restrict__ oh,
    const int* __restrict__ qcount, const int* __restrict__ queue, int qcap)
{
    __shared__ double s1d[D];
    __shared__ double rv[256];
    __shared__ int    rj[256];
    int n = *qcount;
    if (n > qcap) n = qcap;
    const int t = threadIdx.x;
    for (int q = blockIdx.x; q < n; q += gridDim.x) {
        int rg = queue[q];
        int b = rg >> 11, i = rg & (T1 - 1);
        __syncthreads();                      // protect s1d/rv reuse across q
        s1d[t] = (double)s1[((size_t)b * T1 + i) * D + t];
        __syncthreads();
        double bv = -INFINITY; int bj = 0;
        for (int jj = 0; jj < T2 / 256; ++jj) {
            int j = t + jj * 256;             // ascending per thread
            const float* row = s2 + ((size_t)b * T2 + j) * D;
            double s = 0.0;
            for (int k = 0; k < D; ++k) s = fma((double)row[k], s1d[k], s);
            if (s > bv) { bv = s; bj = j; }   // strict >: keep first index
        }
        rv[t] = bv; rj[t] = bj;
        __syncthreads();
        for (int stride = 128; stride > 0; stride >>= 1) {
            if (t < stride) {
                double ov = rv[t + stride]; int oj = rj[t + stride];
                if (ov > rv[t] || (ov == rv[t] && oj < rj[t])) { rv[t] = ov; rj[t] = oj; }
            }
            __syncthreads();
        }
        int best = rj[0];
        float* ohrow = oh + ((size_t)b * T1 + i) * T2;
#pragma unroll
        for (int jj = 0; jj < T2 / 256; ++jj) {
            int j = t + jj * 256;
            ohrow[j] = (j == best) ? 1.f : 0.f;
        }
        u[((size_t)b * T1 + i) * D + t] = s2[((size_t)b * T2 + best) * D + t];
    }
}

extern "C" void kernel_launch(void* const* d_in, const int* in_sizes, int n_in,
                              void* d_out, int out_size, void* d_ws, size_t ws_size,
                              hipStream_t stream)
{
    const float* s1 = (const float*)d_in[0];
    const float* s2 = (const float*)d_in[1];
    float* u  = (float*)d_out;                       // [8,2048,256]
    float* oh = u + (size_t)BB * T1 * D;             // [8,2048,2048]

    int  qcap   = 0;
    int* qcount = nullptr;
    int* queue  = nullptr;
    if (ws_size >= 256) {
        qcount = (int*)d_ws;
        queue  = (int*)d_ws + 4;
        size_t cap = (ws_size - 16) / sizeof(int);
        qcap = (int)(cap > (size_t)(BB * T1) ? (size_t)(BB * T1) : cap);
        hipMemsetAsync(d_ws, 0, 16, stream);         // zero queue counter (capturable)
    }

    k_score_argmax<<<dim3(BB * (T1 / BM)), dim3(256), 0, stream>>>(
        s1, s2, u, oh, qcount, queue, qcap);
    if (qcap > 0)
        k_fixup<<<dim3(64), dim3(256), 0, stream>>>(
            s1, s2, u, oh, qcount, queue, qcap);
}

// Round 2
// 342.670 us; speedup vs baseline: 1.9887x; 1.9887x over previous
//
#include <hip/hip_runtime.h>
#include <math.h>

constexpr int BB = 8, T1 = 2048, T2 = 2048, D = 256;
constexpr int BM = 64;            // rows per block
constexpr int BJ = 256;           // j-columns per block iteration
constexpr int AST = 264;          // A LDS stride (shorts): 256+8, keeps 16B align, 2-way banks
constexpr int BST = 72;           // B LDS stride (shorts): 64+8
constexpr float MARGIN = 4e-3f;   // 3-split bf16 error ~3e-4; 13x headroom

typedef __attribute__((ext_vector_type(8))) __bf16 bf16x8;
typedef __attribute__((ext_vector_type(4))) float  f32x4;

// fp32 -> bf16 bits, round-to-nearest-even
__device__ __forceinline__ unsigned f2bf(float x) {
    unsigned u = __float_as_uint(x);
    return (u + 0x7fffu + ((u >> 16) & 1u)) >> 16;
}
__device__ __forceinline__ float bf2f(unsigned h) { return __uint_as_float(h << 16); }

// K1: bf16 hi/lo 3-split MFMA scores + per-row top-2 argmax + one-hot/gather epilogue.
__global__ __launch_bounds__(512, 2) void k_score_argmax(
    const float* __restrict__ s1, const float* __restrict__ s2,
    float* __restrict__ u, float* __restrict__ oh,
    int* __restrict__ qcount, int* __restrict__ queue, int qcap)
{
    __shared__ __align__(16) short Ah[BM * AST];   // 33792 B
    __shared__ __align__(16) short Al[BM * AST];   // 33792 B
    __shared__ __align__(16) short Bh[BJ * BST];   // 36864 B
    __shared__ __align__(16) short Bl[BJ * BST];   // 36864 B
    __shared__ float cv1[BM][4], cv2[BM][4];
    __shared__ int   ci1[BM][4], idx_s[BM];

    const int bx = blockIdx.x;
    const int b  = bx & 7;                 // batch -> XCD locality for s2 slice
    const int r0 = (bx >> 3) * BM;
    const float* s1b = s1 + ((size_t)b * T1 + r0) * D;
    const float* s2b = s2 + (size_t)b * T2 * D;

    const int t = threadIdx.x;
    const int w = t >> 6, l = t & 63, q = l >> 4, ln = l & 15;
    const int rh = w >> 2;                 // row half (32 rows)
    const int jq = w & 3;                  // j quarter (64 cols of BJ)

    // ---- A prefetch (64 rows x 256 k fp32) ----
    float4 pa[8];
#pragma unroll
    for (int i = 0; i < 8; ++i) {
        int flat = i * 512 + t, row = flat >> 6, f4 = flat & 63;
        pa[i] = *(const float4*)(s1b + row * D + f4 * 4);
    }
    // ---- B chunk 0 prefetch (256 j x 64 k fp32) ----
    float4 pb[8];
#pragma unroll
    for (int i = 0; i < 8; ++i) {
        int flat = i * 512 + t, jrow = flat >> 4, f4 = flat & 15;
        pb[i] = *(const float4*)(s2b + (size_t)jrow * D + f4 * 4);
    }
    // ---- A convert + LDS write ----
#pragma unroll
    for (int i = 0; i < 8; ++i) {
        int flat = i * 512 + t, row = flat >> 6, f4 = flat & 63;
        float4 v = pa[i];
        unsigned hx = f2bf(v.x), hy = f2bf(v.y), hz = f2bf(v.z), hw = f2bf(v.w);
        uint2 hh, ll;
        hh.x = hx | (hy << 16); hh.y = hz | (hw << 16);
        ll.x = f2bf(v.x - bf2f(hx)) | (f2bf(v.y - bf2f(hy)) << 16);
        ll.y = f2bf(v.z - bf2f(hz)) | (f2bf(v.w - bf2f(hw)) << 16);
        *(uint2*)(&Ah[row * AST + f4 * 4]) = hh;
        *(uint2*)(&Al[row * AST + f4 * 4]) = ll;
    }

    float v1[2][4], v2[2][4]; int i1[2][4];
#pragma unroll
    for (int rt = 0; rt < 2; ++rt)
#pragma unroll
        for (int r = 0; r < 4; ++r) { v1[rt][r] = -INFINITY; v2[rt][r] = -INFINITY; i1[rt][r] = 0; }

    f32x4 acc[2][4];

    for (int c = 0; c < 32; ++c) {         // 8 j-iters x 4 k-chunks
        const int iter = c >> 2, kc = c & 3;
        if (kc == 0) {
#pragma unroll
            for (int rt = 0; rt < 2; ++rt)
#pragma unroll
                for (int jt = 0; jt < 4; ++jt)
#pragma unroll
                    for (int r = 0; r < 4; ++r) acc[rt][jt][r] = 0.f;
        }
        __syncthreads();                   // previous chunk fully consumed
        // convert + write current B chunk
#pragma unroll
        for (int i = 0; i < 8; ++i) {
            int flat = i * 512 + t, jrow = flat >> 4, f4 = flat & 15;
            float4 v = pb[i];
            unsigned hx = f2bf(v.x), hy = f2bf(v.y), hz = f2bf(v.z), hw = f2bf(v.w);
            uint2 hh, ll;
            hh.x = hx | (hy << 16); hh.y = hz | (hw << 16);
            ll.x = f2bf(v.x - bf2f(hx)) | (f2bf(v.y - bf2f(hy)) << 16);
            ll.y = f2bf(v.z - bf2f(hz)) | (f2bf(v.w - bf2f(hw)) << 16);
            *(uint2*)(&Bh[jrow * BST + f4 * 4]) = hh;
            *(uint2*)(&Bl[jrow * BST + f4 * 4]) = ll;
        }
        // prefetch next chunk while this one computes
        if (c < 31) {
            int c2 = c + 1, it2 = c2 >> 2, kc2 = c2 & 3;
#pragma unroll
            for (int i = 0; i < 8; ++i) {
                int flat = i * 512 + t, jrow = flat >> 4, f4 = flat & 15;
                pb[i] = *(const float4*)(s2b + (size_t)(it2 * BJ + jrow) * D + kc2 * 64 + f4 * 4);
            }
        }
        __syncthreads();                   // chunk visible

#pragma unroll
        for (int ks = 0; ks < 2; ++ks) {
            const int kA = kc * 64 + ks * 32 + q * 8;
            bf16x8 ah[2], al8[2];
#pragma unroll
            for (int rt = 0; rt < 2; ++rt) {
                int off = (rh * 32 + rt * 16 + ln) * AST + kA;
                ah[rt]  = *(const bf16x8*)(&Ah[off]);
                al8[rt] = *(const bf16x8*)(&Al[off]);
            }
#pragma unroll
            for (int jt = 0; jt < 4; ++jt) {
                int boff = (jq * 64 + jt * 16 + ln) * BST + ks * 32 + q * 8;
                bf16x8 bh = *(const bf16x8*)(&Bh[boff]);
                bf16x8 bl = *(const bf16x8*)(&Bl[boff]);
#pragma unroll
                for (int rt = 0; rt < 2; ++rt) {
                    acc[rt][jt] = __builtin_amdgcn_mfma_f32_16x16x32_bf16(ah[rt],  bh, acc[rt][jt], 0, 0, 0);
                    acc[rt][jt] = __builtin_amdgcn_mfma_f32_16x16x32_bf16(ah[rt],  bl, acc[rt][jt], 0, 0, 0);
                    acc[rt][jt] = __builtin_amdgcn_mfma_f32_16x16x32_bf16(al8[rt], bh, acc[rt][jt], 0, 0, 0);
                }
            }
        }

        if (kc == 3) {                     // full-K scores ready: top-2 update
#pragma unroll
            for (int rt = 0; rt < 2; ++rt)
#pragma unroll
                for (int jt = 0; jt < 4; ++jt)
#pragma unroll
                    for (int r = 0; r < 4; ++r) {
                        float val = acc[rt][jt][r];
                        int j = iter * BJ + jq * 64 + jt * 16 + ln;   // ascending in (iter, jt)
                        if (val > v1[rt][r]) { v2[rt][r] = v1[rt][r]; v1[rt][r] = val; i1[rt][r] = j; }
                        else if (val > v2[rt][r]) v2[rt][r] = val;
                    }
        }
    }

    // reduce top-2 across the 16 lanes sharing quad q (rows identical there)
#pragma unroll
    for (int rt = 0; rt < 2; ++rt)
#pragma unroll
        for (int r = 0; r < 4; ++r) {
            float a1 = v1[rt][r], a2 = v2[rt][r]; int ai = i1[rt][r];
#pragma unroll
            for (int off = 1; off < 16; off <<= 1) {
                float b1 = __shfl_xor(a1, off);
                int   bi = __shfl_xor(ai, off);
                float b2 = __shfl_xor(a2, off);
                if (b1 > a1 || (b1 == a1 && bi < ai)) { a2 = fmaxf(a1, b2); a1 = b1; ai = bi; }
                else                                   { a2 = fmaxf(b1, a2); }
            }
            if (ln == 0) {
                int row = rh * 32 + rt * 16 + q * 4 + r;
                cv1[row][jq] = a1; cv2[row][jq] = a2; ci1[row][jq] = ai;
            }
        }
    __syncthreads();

    if (t < BM) {                          // merge the 4 j-quarter waves per row
        float V1 = cv1[t][0], V2 = cv2[t][0]; int I = ci1[t][0];
#pragma unroll
        for (int h = 1; h < 4; ++h) {
            float c1 = cv1[t][h], c2 = cv2[t][h]; int ci = ci1[t][h];
            if (c1 > V1 || (c1 == V1 && ci < I)) { V2 = fmaxf(V1, c2); V1 = c1; I = ci; }
            else                                  { V2 = fmaxf(V2, c1); }
        }
        idx_s[t] = I;
        if (qcap > 0 && (V1 - V2) < MARGIN) {
            int pos = atomicAdd(qcount, 1);
            if (pos < qcap) queue[pos] = b * T1 + r0 + t;
        }
    }
    __syncthreads();

    // epilogue: u_tile gather (coalesced) then one-hot stream
    float* ub = u + ((size_t)b * T1 + r0) * D;
#pragma unroll
    for (int i = 0; i < 8; ++i) {
        int flat = i * 512 + t, row = flat >> 6, f4 = flat & 63;
        float4 v = *(const float4*)(s2b + (size_t)idx_s[row] * D + f4 * 4);
        *(float4*)(ub + (size_t)row * D + f4 * 4) = v;
    }
    float* ohb = oh + ((size_t)b * T1 + r0) * T2;
#pragma unroll 4
    for (int i = 0; i < 64; ++i) {
        int flat = i * 512 + t, row = flat >> 9, f4 = flat & 511;
        int base = f4 * 4, id = idx_s[row];
        float4 vv;
        vv.x = (base     == id) ? 1.f : 0.f;
        vv.y = (base + 1 == id) ? 1.f : 0.f;
        vv.z = (base + 2 == id) ? 1.f : 0.f;
        vv.w = (base + 3 == id) ? 1.f : 0.f;
        *(float4*)(ohb + (size_t)row * T2 + base) = vv;
    }
}

// K2: exact float64 recompute for flagged (near-tie) rows; rewrites their outputs.
__global__ __launch_bounds__(256) void k_fixup(
    const float* __restrict__ s1, const float* __restrict__ s2,
    float* __restrict__ u, float* __restrict__ oh,
    const int* __restrict__ qcount, const int* __restrict__ queue, int qcap)
{
    __shared__ double s1d[D];
    __shared__ double rv[256];
    __shared__ int    rj[256];
    int n = *qcount;
    if (n > qcap) n = qcap;
    const int t = threadIdx.x;
    for (int qi = blockIdx.x; qi < n; qi += gridDim.x) {
        int rg = queue[qi];
        int b = rg >> 11, i = rg & (T1 - 1);
        __syncthreads();
        s1d[t] = (double)s1[((size_t)b * T1 + i) * D + t];
        __syncthreads();
        double bv = -INFINITY; int bj = 0;
        for (int jj = 0; jj < T2 / 256; ++jj) {
            int j = t + jj * 256;
            const float* row = s2 + ((size_t)b * T2 + j) * D;
            double s = 0.0;
            for (int k = 0; k < D; ++k) s = fma((double)row[k], s1d[k], s);
            if (s > bv) { bv = s; bj = j; }
        }
        rv[t] = bv; rj[t] = bj;
        __syncthreads();
        for (int stride = 128; stride > 0; stride >>= 1) {
            if (t < stride) {
                double ov = rv[t + stride]; int oj = rj[t + stride];
                if (ov > rv[t] || (ov == rv[t] && oj < rj[t])) { rv[t] = ov; rj[t] = oj; }
            }
            __syncthreads();
        }
        int best = rj[0];
        float* ohrow = oh + ((size_t)b * T1 + i) * T2;
#pragma unroll
        for (int jj = 0; jj < T2 / 256; ++jj) {
            int j = t + jj * 256;
            ohrow[j] = (j == best) ? 1.f : 0.f;
        }
        u[((size_t)b * T1 + i) * D + t] = s2[((size_t)b * T2 + best) * D + t];
    }
}

extern "C" void kernel_launch(void* const* d_in, const int* in_sizes, int n_in,
                              void* d_out, int out_size, void* d_ws, size_t ws_size,
                              hipStream_t stream)
{
    const float* s1 = (const float*)d_in[0];
    const float* s2 = (const float*)d_in[1];
    float* u  = (float*)d_out;                       // [8,2048,256]
    float* oh = u + (size_t)BB * T1 * D;             // [8,2048,2048]

    int  qcap   = 0;
    int* qcount = nullptr;
    int* queue  = nullptr;
    if (ws_size >= 256) {
        qcount = (int*)d_ws;
        queue  = (int*)d_ws + 4;
        size_t cap = (ws_size - 16) / sizeof(int);
        qcap = (int)(cap > (size_t)(BB * T1) ? (size_t)(BB * T1) : cap);
        hipMemsetAsync(d_ws, 0, 16, stream);
    }

    k_score_argmax<<<dim3(BB * (T1 / BM)), dim3(512), 0, stream>>>(
        s1, s2, u, oh, qcount, queue, qcap);
    if (qcap > 0)
        k_fixup<<<dim3(64), dim3(256), 0, stream>>>(
            s1, s2, u, oh, qcount, queue, qcap);
}

// Round 4
// 312.791 us; speedup vs baseline: 2.1787x; 1.0955x over previous
//
#include <hip/hip_runtime.h>
#include <math.h>

typedef unsigned short ushort_t;

constexpr int BB = 8, T1 = 2048, T2 = 2048, D = 256;
constexpr float MARGIN = 4e-3f;   // 3-limb bf16 score error ~1e-4; 40x headroom

// ---- workspace layout (fast path) ----
constexpr size_t OFF_QC    = 0;                         // int counter (16 B)
constexpr size_t OFF_QUEUE = 64;                        // 16384 ints
constexpr size_t OFF_PART  = 131072;                    // float4[16384*4] = 1 MB
constexpr size_t OFF_S1P   = (size_t)2 << 20;           // packed bf16 hi/lo s1 (16.8 MB)
constexpr size_t SZ_PACK   = (size_t)BB * 128 * 8 * 2 * 64 * 16; // b*tile16*g*limb*lane*16B
constexpr size_t OFF_S2P   = OFF_S1P + SZ_PACK;
constexpr size_t WS_NEEDED = OFF_S2P + SZ_PACK;         // ~35.7 MB

typedef __attribute__((ext_vector_type(8))) __bf16 bf16x8;
typedef __attribute__((ext_vector_type(4))) float  f32x4;

__device__ __forceinline__ unsigned f2bf(float x) {
    unsigned u = __float_as_uint(x);
    return (u + 0x7fffu + ((u >> 16) & 1u)) >> 16;
}
__device__ __forceinline__ float bf2f(unsigned h) { return __uint_as_float(h << 16); }

// ============================================================================
// K0: convert fp32 -> bf16 hi/lo, packed in MFMA-fragment tile order.
// Tile = 16 rows x 32 k. Chunk (1 KB) = [lane 0..63][8 shorts],
// lane = (row&15) + 16*((k&31)>>3), element i -> k = (lane>>4)*8 + i.
// Flat: [b][tile16 (128)][g (8)][limb (2)][lane (64)][16 B].
// ============================================================================
__global__ __launch_bounds__(256) void k_convert(
    const float* __restrict__ s1, const float* __restrict__ s2,
    ushort_t* __restrict__ s1p, ushort_t* __restrict__ s2p)
{
    __shared__ __align__(16) ushort_t L[16384];   // 32 KB staging (2 tile16 of output)
    const int bx = blockIdx.x;
    const int tensor = bx >> 9, b = (bx >> 6) & 7, rt = bx & 63;  // rt: 32-row group
    const float* src = (tensor ? s2 : s1) + ((size_t)b * 2048 + rt * 32) * 256;
    ushort_t* dst = (tensor ? s2p : s1p) + (size_t)(b * 128 + rt * 2) * 8192;
    const int t = threadIdx.x;
#pragma unroll
    for (int i = 0; i < 8; ++i) {
        int f = i * 256 + t, rw = f >> 6, c4 = f & 63, k0 = c4 * 4;
        float4 v = *(const float4*)(src + rw * 256 + k0);
        unsigned hx = f2bf(v.x), hy = f2bf(v.y), hz = f2bf(v.z), hw = f2bf(v.w);
        ushort4 hi = make_ushort4((ushort_t)hx, (ushort_t)hy, (ushort_t)hz, (ushort_t)hw);
        ushort4 lo = make_ushort4((ushort_t)f2bf(v.x - bf2f(hx)), (ushort_t)f2bf(v.y - bf2f(hy)),
                                  (ushort_t)f2bf(v.z - bf2f(hz)), (ushort_t)f2bf(v.w - bf2f(hw)));
        int tile = rw >> 4, m = rw & 15, g = k0 >> 5;
        int lane = m + 16 * ((k0 >> 3) & 3), i0 = k0 & 7;
        int off = (tile * 8 + g) * 1024 + lane * 8 + i0;   // limb stride 512 shorts
        *(ushort4*)(&L[off])       = hi;
        *(ushort4*)(&L[off + 512]) = lo;
    }
    __syncthreads();
#pragma unroll
    for (int i = 0; i < 8; ++i) {
        int cidx = i * 256 + t;                             // 2048 x 16 B = 32 KB
        ((uint4*)dst)[cidx] = ((const uint4*)L)[cidx];
    }
}

// ============================================================================
// K1: scores via 3-limb bf16 MFMA (16x16x32, HW-verified layout), per-row
// top-2 over this block's j-quarter; writes partial (v1,v2,idx) to ws.
// Grid 512: b=bx&7 (XCD locality), rt16=(bx>>3)&15 (128 rows), jq=bx>>7 (512 j).
// Block 256 thr = 4 waves: rh=w>>1 (64-row half), jw=w&1 (128-j half).
// Wave tile 64x128 = rt4 x jt8.
// ============================================================================
__global__ __launch_bounds__(256, 2) void k_score(
    const ushort_t* __restrict__ s1p, const ushort_t* __restrict__ s2p,
    float4* __restrict__ part)
{
    __shared__ __align__(16) ushort_t AL[16 * 512];   // 8 tile16 x 2 limb, 16 KB
    __shared__ __align__(16) ushort_t BL[32 * 512];   // 16 tile16 x 2 limb, 32 KB
    __shared__ float4 mrg[128][2];

    const int bx = blockIdx.x;
    const int b = bx & 7, rt16 = (bx >> 3) & 15, jq = bx >> 7;
    const int t = threadIdx.x, w = t >> 6, l = t & 63;
    const int rh = w >> 1, jw = w & 1;
    const int q = l >> 4, n = l & 15;

    mrg[t >> 1][t & 1] = make_float4(-INFINITY, -INFINITY, __int_as_float(0), 0.f);

    const ushort_t* Abase = s1p + (size_t)(b * 128 + rt16 * 8) * 8192;

    f32x4 acc[4][8];

    for (int jiter = 0; jiter < 2; ++jiter) {
        const ushort_t* Bbase = s2p + (size_t)(b * 128 + jq * 32 + jiter * 16) * 8192;
#pragma unroll
        for (int rtl = 0; rtl < 4; ++rtl)
#pragma unroll
            for (int jt = 0; jt < 8; ++jt)
#pragma unroll
                for (int r = 0; r < 4; ++r) acc[rtl][jt][r] = 0.f;

        for (int g = 0; g < 8; ++g) {
            __syncthreads();   // previous chunk consumed
            // FIX (r4): AL holds only the CURRENT g's A fragments, so A must be
            // re-staged every g in BOTH jiters. r3 skipped A staging on jiter 1
            // (cbase=16) -> jiter-1 scores used stale g=7 A data -> wrong argmax.
            for (int s = 0; s * 4 < 48; ++s) {
                int c = s * 4 + w;
                uint4 v;
                if (c < 16)
                    v = *(const uint4*)(Abase + (size_t)(c >> 1) * 8192 + g * 1024 + (c & 1) * 512 + l * 8);
                else {
                    int cc = c - 16;
                    v = *(const uint4*)(Bbase + (size_t)(cc >> 1) * 8192 + g * 1024 + (cc & 1) * 512 + l * 8);
                }
                if (c < 16) *(uint4*)(&AL[c * 512 + l * 8]) = v;
                else        *(uint4*)(&BL[(c - 16) * 512 + l * 8]) = v;
            }
            __syncthreads();

            bf16x8 aF[4][2];
#pragma unroll
            for (int rtl = 0; rtl < 4; ++rtl)
#pragma unroll
                for (int lb = 0; lb < 2; ++lb)
                    aF[rtl][lb] = *(const bf16x8*)(&AL[((rh * 4 + rtl) * 2 + lb) * 512 + l * 8]);
#pragma unroll
            for (int jt = 0; jt < 8; ++jt) {
                bf16x8 bh = *(const bf16x8*)(&BL[((jw * 8 + jt) * 2 + 0) * 512 + l * 8]);
                bf16x8 bl = *(const bf16x8*)(&BL[((jw * 8 + jt) * 2 + 1) * 512 + l * 8]);
#pragma unroll
                for (int rtl = 0; rtl < 4; ++rtl) {
                    acc[rtl][jt] = __builtin_amdgcn_mfma_f32_16x16x32_bf16(aF[rtl][0], bh, acc[rtl][jt], 0, 0, 0);
                    acc[rtl][jt] = __builtin_amdgcn_mfma_f32_16x16x32_bf16(aF[rtl][0], bl, acc[rtl][jt], 0, 0, 0);
                    acc[rtl][jt] = __builtin_amdgcn_mfma_f32_16x16x32_bf16(aF[rtl][1], bh, acc[rtl][jt], 0, 0, 0);
                }
            }
        }

        // top-2 per row over this jiter's 256 j (per wave: its 128-j half)
#pragma unroll
        for (int rtl = 0; rtl < 4; ++rtl)
#pragma unroll
            for (int reg = 0; reg < 4; ++reg) {
                float v1 = -INFINITY, v2 = -INFINITY; int i1 = 0;
#pragma unroll
                for (int jt = 0; jt < 8; ++jt) {
                    float v = acc[rtl][jt][reg];
                    int j = jq * 512 + jiter * 256 + jw * 128 + jt * 16 + n;  // ascending in jt
                    if (v > v1)      { v2 = v1; v1 = v; i1 = j; }
                    else if (v > v2) { v2 = v; }
                }
#pragma unroll
                for (int off = 1; off < 16; off <<= 1) {
                    float b1 = __shfl_xor(v1, off);
                    int   bi = __shfl_xor(i1, off);
                    float b2 = __shfl_xor(v2, off);
                    if (b1 > v1 || (b1 == v1 && bi < i1)) { v2 = fmaxf(v1, b2); v1 = b1; i1 = bi; }
                    else                                   { v2 = fmaxf(b1, v2); }
                }
                int rr = rtl * 4 + reg;
                if (n == rr) {   // 4 active lanes (one per quad), distinct rows
                    int row = rh * 64 + rtl * 16 + q * 4 + reg;
                    float4 cur = mrg[row][jw];
                    int ci = __float_as_int(cur.z);
                    if (v1 > cur.x || (v1 == cur.x && i1 < ci))
                        mrg[row][jw] = make_float4(v1, fmaxf(v2, cur.x), __int_as_float(i1), 0.f);
                    else
                        mrg[row][jw] = make_float4(cur.x, fmaxf(cur.y, v1), cur.z, 0.f);
                }
            }
    }

    __syncthreads();
    if (t < 128) {
        float4 p0 = mrg[t][0], p1 = mrg[t][1];
        int i0 = __float_as_int(p0.z), i1 = __float_as_int(p1.z);
        float v1, v2; int ii;
        if (p1.x > p0.x || (p1.x == p0.x && i1 < i0)) { v1 = p1.x; v2 = fmaxf(p1.y, p0.x); ii = i1; }
        else                                          { v1 = p0.x; v2 = fmaxf(p0.y, p1.x); ii = i0; }
        part[((size_t)b * 2048 + rt16 * 128 + t) * 4 + jq] =
            make_float4(v1, v2, __int_as_float(ii), 0.f);
    }
}

// ============================================================================
// K2: merge 4 j-quarter partials per row, flag near-ties, write one-hot + u.
// 2048 blocks x 256 thr, 8 rows per block. Pure streaming stores (HBM-bound).
// ============================================================================
__global__ __launch_bounds__(256) void k_epilogue(
    const float* __restrict__ s2, const float4* __restrict__ part,
    float* __restrict__ u, float* __restrict__ oh,
    int* __restrict__ qcount, int* __restrict__ queue)
{
    __shared__ int idxs[8];
    const int blk = blockIdx.x, t = threadIdx.x;
    const int r0 = blk * 8;
    const int b = r0 >> 11;
    if (t < 32) {
        int rl = t >> 2, p = t & 3;
        float4 pa = part[(size_t)(r0 + rl) * 4 + p];
        float v1 = pa.x, v2 = pa.y; int i1 = __float_as_int(pa.z);
#pragma unroll
        for (int off = 1; off < 4; off <<= 1) {
            float b1 = __shfl_xor(v1, off);
            int   bi = __shfl_xor(i1, off);
            float b2 = __shfl_xor(v2, off);
            if (b1 > v1 || (b1 == v1 && bi < i1)) { v2 = fmaxf(v1, b2); v1 = b1; i1 = bi; }
            else                                   { v2 = fmaxf(b1, v2); }
        }
        if (p == 0) {
            idxs[rl] = i1;
            if ((v1 - v2) < MARGIN) {
                int pos = atomicAdd(qcount, 1);
                if (pos < 16384) queue[pos] = r0 + rl;
            }
        }
    }
    __syncthreads();
    const float* s2b = s2 + (size_t)b * T2 * D;
    float* ub = u + (size_t)r0 * D;
#pragma unroll
    for (int i = 0; i < 2; ++i) {
        int flat = i * 256 + t, rl = flat >> 6, c = flat & 63;
        float4 v = *(const float4*)(s2b + (size_t)idxs[rl] * D + c * 4);
        *(float4*)(ub + (size_t)rl * D + c * 4) = v;
    }
    float* ohb = oh + (size_t)r0 * T2;
#pragma unroll 4
    for (int i = 0; i < 16; ++i) {
        int flat = i * 256 + t, rl = flat >> 9, c4 = flat & 511;
        int base = c4 * 4, id = idxs[rl];
        float4 vv;
        vv.x = (base     == id) ? 1.f : 0.f;
        vv.y = (base + 1 == id) ? 1.f : 0.f;
        vv.z = (base + 2 == id) ? 1.f : 0.f;
        vv.w = (base + 3 == id) ? 1.f : 0.f;
        *(float4*)(ohb + (size_t)rl * T2 + base) = vv;
    }
}

// ============================================================================
// K3: exact float64 recompute for flagged (near-tie) rows.
// ============================================================================
__global__ __launch_bounds__(256) void k_fixup(
    const float* __restrict__ s1, const float* __restrict__ s2,
    float* __restrict__ u, float* __restrict__ oh,
    const int* __restrict__ qcount, const int* __restrict__ queue, int qcap)
{
    __shared__ double s1d[D];
    __shared__ double rv[256];
    __shared__ int    rj[256];
    int nq = *qcount;
    if (nq > qcap) nq = qcap;
    const int t = threadIdx.x;
    for (int qi = blockIdx.x; qi < nq; qi += gridDim.x) {
        int rg = queue[qi];
        int b = rg >> 11, i = rg & (T1 - 1);
        __syncthreads();
        s1d[t] = (double)s1[((size_t)b * T1 + i) * D + t];
        __syncthreads();
        double bv = -INFINITY; int bj = 0;
        for (int jj = 0; jj < T2 / 256; ++jj) {
            int j = t + jj * 256;
            const float* row = s2 + ((size_t)b * T2 + j) * D;
            double s = 0.0;
            for (int k = 0; k < D; ++k) s = fma((double)row[k], s1d[k], s);
            if (s > bv) { bv = s; bj = j; }
        }
        rv[t] = bv; rj[t] = bj;
        __syncthreads();
        for (int stride = 128; stride > 0; stride >>= 1) {
            if (t < stride) {
                double ov = rv[t + stride]; int oj = rj[t + stride];
                if (ov > rv[t] || (ov == rv[t] && oj < rj[t])) { rv[t] = ov; rj[t] = oj; }
            }
            __syncthreads();
        }
        int best = rj[0];
        float* ohrow = oh + ((size_t)b * T1 + i) * T2;
#pragma unroll
        for (int jj = 0; jj < T2 / 256; ++jj) {
            int j = t + jj * 256;
            ohrow[j] = (j == best) ? 1.f : 0.f;
        }
        u[((size_t)b * T1 + i) * D + t] = s2[((size_t)b * T2 + best) * D + t];
    }
}

// ============================================================================
// Fallback (ws too small): round-2 fused kernel, verified correct.
// ============================================================================
constexpr int FB_AST = 264, FB_BST = 72;

__global__ __launch_bounds__(512, 2) void k_score_fb(
    const float* __restrict__ s1, const float* __restrict__ s2,
    float* __restrict__ u, float* __restrict__ oh,
    int* __restrict__ qcount, int* __restrict__ queue, int qcap)
{
    __shared__ __align__(16) short Ah[64 * FB_AST];
    __shared__ __align__(16) short Al[64 * FB_AST];
    __shared__ __align__(16) short Bh[256 * FB_BST];
    __shared__ __align__(16) short Bl[256 * FB_BST];
    __shared__ float cv1[64][4], cv2[64][4];
    __shared__ int   ci1[64][4], idx_s[64];

    const int bx = blockIdx.x;
    const int b  = bx & 7;
    const int r0 = (bx >> 3) * 64;
    const float* s1b = s1 + ((size_t)b * T1 + r0) * D;
    const float* s2b = s2 + (size_t)b * T2 * D;

    const int t = threadIdx.x;
    const int w = t >> 6, l = t & 63, q = l >> 4, ln = l & 15;
    const int rh = w >> 2;
    const int jq = w & 3;

    float4 pa[8];
#pragma unroll
    for (int i = 0; i < 8; ++i) {
        int flat = i * 512 + t, row = flat >> 6, f4 = flat & 63;
        pa[i] = *(const float4*)(s1b + row * D + f4 * 4);
    }
    float4 pb[8];
#pragma unroll
    for (int i = 0; i < 8; ++i) {
        int flat = i * 512 + t, jrow = flat >> 4, f4 = flat & 15;
        pb[i] = *(const float4*)(s2b + (size_t)jrow * D + f4 * 4);
    }
#pragma unroll
    for (int i = 0; i < 8; ++i) {
        int flat = i * 512 + t, row = flat >> 6, f4 = flat & 63;
        float4 v = pa[i];
        unsigned hx = f2bf(v.x), hy = f2bf(v.y), hz = f2bf(v.z), hw = f2bf(v.w);
        uint2 hh, ll;
        hh.x = hx | (hy << 16); hh.y = hz | (hw << 16);
        ll.x = f2bf(v.x - bf2f(hx)) | (f2bf(v.y - bf2f(hy)) << 16);
        ll.y = f2bf(v.z - bf2f(hz)) | (f2bf(v.w - bf2f(hw)) << 16);
        *(uint2*)(&Ah[row * FB_AST + f4 * 4]) = hh;
        *(uint2*)(&Al[row * FB_AST + f4 * 4]) = ll;
    }

    float v1[2][4], v2[2][4]; int i1[2][4];
#pragma unroll
    for (int rt = 0; rt < 2; ++rt)
#pragma unroll
        for (int r = 0; r < 4; ++r) { v1[rt][r] = -INFINITY; v2[rt][r] = -INFINITY; i1[rt][r] = 0; }

    f32x4 acc[2][4];

    for (int c = 0; c < 32; ++c) {
        const int iter = c >> 2, kc = c & 3;
        if (kc == 0) {
#pragma unroll
            for (int rt = 0; rt < 2; ++rt)
#pragma unroll
                for (int jt = 0; jt < 4; ++jt)
#pragma unroll
                    for (int r = 0; r < 4; ++r) acc[rt][jt][r] = 0.f;
        }
        __syncthreads();
#pragma unroll
        for (int i = 0; i < 8; ++i) {
            int flat = i * 512 + t, jrow = flat >> 4, f4 = flat & 15;
            float4 v = pb[i];
            unsigned hx = f2bf(v.x), hy = f2bf(v.y), hz = f2bf(v.z), hw = f2bf(v.w);
            uint2 hh, ll;
            hh.x = hx | (hy << 16); hh.y = hz | (hw << 16);
            ll.x = f2bf(v.x - bf2f(hx)) | (f2bf(v.y - bf2f(hy)) << 16);
            ll.y = f2bf(v.z - bf2f(hz)) | (f2bf(v.w - bf2f(hw)) << 16);
            *(uint2*)(&Bh[jrow * FB_BST + f4 * 4]) = hh;
            *(uint2*)(&Bl[jrow * FB_BST + f4 * 4]) = ll;
        }
        if (c < 31) {
            int c2 = c + 1, it2 = c2 >> 2, kc2 = c2 & 3;
#pragma unroll
            for (int i = 0; i < 8; ++i) {
                int flat = i * 512 + t, jrow = flat >> 4, f4 = flat & 15;
                pb[i] = *(const float4*)(s2b + (size_t)(it2 * 256 + jrow) * D + kc2 * 64 + f4 * 4);
            }
        }
        __syncthreads();

#pragma unroll
        for (int ks = 0; ks < 2; ++ks) {
            const int kA = kc * 64 + ks * 32 + q * 8;
            bf16x8 ah[2], al8[2];
#pragma unroll
            for (int rt = 0; rt < 2; ++rt) {
                int off = (rh * 32 + rt * 16 + ln) * FB_AST + kA;
                ah[rt]  = *(const bf16x8*)(&Ah[off]);
                al8[rt] = *(const bf16x8*)(&Al[off]);
            }
#pragma unroll
            for (int jt = 0; jt < 4; ++jt) {
                int boff = (jq * 64 + jt * 16 + ln) * FB_BST + ks * 32 + q * 8;
                bf16x8 bh = *(const bf16x8*)(&Bh[boff]);
                bf16x8 bl = *(const bf16x8*)(&Bl[boff]);
#pragma unroll
                for (int rt = 0; rt < 2; ++rt) {
                    acc[rt][jt] = __builtin_amdgcn_mfma_f32_16x16x32_bf16(ah[rt],  bh, acc[rt][jt], 0, 0, 0);
                    acc[rt][jt] = __builtin_amdgcn_mfma_f32_16x16x32_bf16(ah[rt],  bl, acc[rt][jt], 0, 0, 0);
                    acc[rt][jt] = __builtin_amdgcn_mfma_f32_16x16x32_bf16(al8[rt], bh, acc[rt][jt], 0, 0, 0);
                }
            }
        }

        if (kc == 3) {
#pragma unroll
            for (int rt = 0; rt < 2; ++rt)
#pragma unroll
                for (int jt = 0; jt < 4; ++jt)
#pragma unroll
                    for (int r = 0; r < 4; ++r) {
                        float val = acc[rt][jt][r];
                        int j = iter * 256 + jq * 64 + jt * 16 + ln;
                        if (val > v1[rt][r]) { v2[rt][r] = v1[rt][r]; v1[rt][r] = val; i1[rt][r] = j; }
                        else if (val > v2[rt][r]) v2[rt][r] = val;
                    }
        }
    }

#pragma unroll
    for (int rt = 0; rt < 2; ++rt)
#pragma unroll
        for (int r = 0; r < 4; ++r) {
            float a1 = v1[rt][r], a2 = v2[rt][r]; int ai = i1[rt][r];
#pragma unroll
            for (int off = 1; off < 16; off <<= 1) {
                float b1 = __shfl_xor(a1, off);
                int   bi = __shfl_xor(ai, off);
                float b2 = __shfl_xor(a2, off);
                if (b1 > a1 || (b1 == a1 && bi < ai)) { a2 = fmaxf(a1, b2); a1 = b1; ai = bi; }
                else                                   { a2 = fmaxf(b1, a2); }
            }
            if (ln == 0) {
                int row = rh * 32 + rt * 16 + q * 4 + r;
                cv1[row][jq] = a1; cv2[row][jq] = a2; ci1[row][jq] = ai;
            }
        }
    __syncthreads();

    if (t < 64) {
        float V1 = cv1[t][0], V2 = cv2[t][0]; int I = ci1[t][0];
#pragma unroll
        for (int h = 1; h < 4; ++h) {
            float c1 = cv1[t][h], c2 = cv2[t][h]; int ci = ci1[t][h];
            if (c1 > V1 || (c1 == V1 && ci < I)) { V2 = fmaxf(V1, c2); V1 = c1; I = ci; }
            else                                  { V2 = fmaxf(V2, c1); }
        }
        idx_s[t] = I;
        if (qcap > 0 && (V1 - V2) < MARGIN) {
            int pos = atomicAdd(qcount, 1);
            if (pos < qcap) queue[pos] = b * T1 + r0 + t;
        }
    }
    __syncthreads();

    float* ub = u + ((size_t)b * T1 + r0) * D;
#pragma unroll
    for (int i = 0; i < 8; ++i) {
        int flat = i * 512 + t, row = flat >> 6, f4 = flat & 63;
        float4 v = *(const float4*)(s2b + (size_t)idx_s[row] * D + f4 * 4);
        *(float4*)(ub + (size_t)row * D + f4 * 4) = v;
    }
    float* ohb = oh + ((size_t)b * T1 + r0) * T2;
#pragma unroll 4
    for (int i = 0; i < 64; ++i) {
        int flat = i * 512 + t, row = flat >> 9, f4 = flat & 511;
        int base = f4 * 4, id = idx_s[row];
        float4 vv;
        vv.x = (base     == id) ? 1.f : 0.f;
        vv.y = (base + 1 == id) ? 1.f : 0.f;
        vv.z = (base + 2 == id) ? 1.f : 0.f;
        vv.w = (base + 3 == id) ? 1.f : 0.f;
        *(float4*)(ohb + (size_t)row * T2 + base) = vv;
    }
}

extern "C" void kernel_launch(void* const* d_in, const int* in_sizes, int n_in,
                              void* d_out, int out_size, void* d_ws, size_t ws_size,
                              hipStream_t stream)
{
    const float* s1 = (const float*)d_in[0];
    const float* s2 = (const float*)d_in[1];
    float* u  = (float*)d_out;                       // [8,2048,256]
    float* oh = u + (size_t)BB * T1 * D;             // [8,2048,2048]
    char* ws = (char*)d_ws;

    if (ws_size >= WS_NEEDED) {
        int*      qc    = (int*)(ws + OFF_QC);
        int*      queue = (int*)(ws + OFF_QUEUE);
        float4*   part  = (float4*)(ws + OFF_PART);
        ushort_t* s1p   = (ushort_t*)(ws + OFF_S1P);
        ushort_t* s2p   = (ushort_t*)(ws + OFF_S2P);
        hipMemsetAsync(ws + OFF_QC, 0, 16, stream);
        k_convert<<<dim3(1024), dim3(256), 0, stream>>>(s1, s2, s1p, s2p);
        k_score<<<dim3(512), dim3(256), 0, stream>>>(s1p, s2p, part);
        k_epilogue<<<dim3(2048), dim3(256), 0, stream>>>(s2, part, u, oh, qc, queue);
        k_fixup<<<dim3(128), dim3(256), 0, stream>>>(s1, s2, u, oh, qc, queue, 16384);
    } else {
        int  qcap   = 0;
        int* qcount = nullptr;
        int* queue  = nullptr;
        if (ws_size >= 256) {
            qcount = (int*)d_ws;
            queue  = (int*)d_ws + 4;
            size_t cap = (ws_size - 16) / sizeof(int);
            qcap = (int)(cap > (size_t)(BB * T1) ? (size_t)(BB * T1) : cap);
            hipMemsetAsync(d_ws, 0, 16, stream);
        }
        k_score_fb<<<dim3(BB * (T1 / 64)), dim3(512), 0, stream>>>(
            s1, s2, u, oh, qcount, queue, qcap);
        if (qcap > 0)
            k_fixup<<<dim3(64), dim3(256), 0, stream>>>(
                s1, s2, u, oh, qcount, queue, qcap);
    }
}

// Round 5
// 306.946 us; speedup vs baseline: 2.2202x; 1.0190x over previous
//
#include <hip/hip_runtime.h>
#include <math.h>

typedef unsigned short ushort_t;

constexpr int BB = 8, T1 = 2048, T2 = 2048, D = 256;
constexpr float MARGIN = 4e-3f;   // 3-limb bf16 score error ~1e-4; 40x headroom

// ---- workspace layout (fast path) ----
constexpr size_t OFF_QC    = 0;                         // int counter (16 B)
constexpr size_t OFF_QUEUE = 64;                        // 16384 ints
constexpr size_t OFF_PART  = 131072;                    // float4[16384*4] = 1 MB
constexpr size_t OFF_S1P   = (size_t)2 << 20;           // packed bf16 hi/lo s1 (16.8 MB)
constexpr size_t SZ_PACK   = (size_t)BB * 128 * 8 * 2 * 64 * 16; // b*tile16*g*limb*lane*16B
constexpr size_t OFF_S2P   = OFF_S1P + SZ_PACK;
constexpr size_t WS_NEEDED = OFF_S2P + SZ_PACK;         // ~35.7 MB

typedef __attribute__((ext_vector_type(8))) __bf16 bf16x8;
typedef __attribute__((ext_vector_type(4))) float  f32x4;

__device__ __forceinline__ unsigned f2bf(float x) {
    unsigned u = __float_as_uint(x);
    return (u + 0x7fffu + ((u >> 16) & 1u)) >> 16;
}
__device__ __forceinline__ float bf2f(unsigned h) { return __uint_as_float(h << 16); }

// ============================================================================
// K0: convert fp32 -> bf16 hi/lo, packed in MFMA-fragment tile order.
// Tile = 16 rows x 32 k. Chunk (1 KB) = [lane 0..63][8 shorts],
// lane = (row&15) + 16*((k&31)>>3), element i -> k = (lane>>4)*8 + i.
// Flat: [b][tile16 (128)][g (8)][limb (2)][lane (64)][16 B].
// ============================================================================
__global__ __launch_bounds__(256) void k_convert(
    const float* __restrict__ s1, const float* __restrict__ s2,
    ushort_t* __restrict__ s1p, ushort_t* __restrict__ s2p)
{
    __shared__ __align__(16) ushort_t L[16384];   // 32 KB staging (2 tile16 of output)
    const int bx = blockIdx.x;
    const int tensor = bx >> 9, b = (bx >> 6) & 7, rt = bx & 63;  // rt: 32-row group
    const float* src = (tensor ? s2 : s1) + ((size_t)b * 2048 + rt * 32) * 256;
    ushort_t* dst = (tensor ? s2p : s1p) + (size_t)(b * 128 + rt * 2) * 8192;
    const int t = threadIdx.x;
#pragma unroll
    for (int i = 0; i < 8; ++i) {
        int f = i * 256 + t, rw = f >> 6, c4 = f & 63, k0 = c4 * 4;
        float4 v = *(const float4*)(src + rw * 256 + k0);
        unsigned hx = f2bf(v.x), hy = f2bf(v.y), hz = f2bf(v.z), hw = f2bf(v.w);
        ushort4 hi = make_ushort4((ushort_t)hx, (ushort_t)hy, (ushort_t)hz, (ushort_t)hw);
        ushort4 lo = make_ushort4((ushort_t)f2bf(v.x - bf2f(hx)), (ushort_t)f2bf(v.y - bf2f(hy)),
                                  (ushort_t)f2bf(v.z - bf2f(hz)), (ushort_t)f2bf(v.w - bf2f(hw)));
        int tile = rw >> 4, m = rw & 15, g = k0 >> 5;
        int lane = m + 16 * ((k0 >> 3) & 3), i0 = k0 & 7;
        int off = (tile * 8 + g) * 1024 + lane * 8 + i0;   // limb stride 512 shorts
        *(ushort4*)(&L[off])       = hi;
        *(ushort4*)(&L[off + 512]) = lo;
    }
    __syncthreads();
#pragma unroll
    for (int i = 0; i < 8; ++i) {
        int cidx = i * 256 + t;                             // 2048 x 16 B = 32 KB
        ((uint4*)dst)[cidx] = ((const uint4*)L)[cidx];
    }
}

// ============================================================================
// K1 (r5): barrier-free, LDS-free score. The packed layout is already exact
// per-lane MFMA fragment order, so each wave loads its A/B fragments straight
// from global into VGPRs (global_load_dwordx4, lane-coalesced 1 KB/chunk) and
// feeds 3-limb bf16 MFMA. No __syncthreads in the K-loop; L1/L2 serve the 2x
// intra-block duplicate reads. Grid 512: b=bx&7, rt16 (128 rows), jq (512 j).
// Block 256 thr = 4 waves: rh=w>>1 (64-row half), jw=w&1 (128-j half of the
// 256-j jiter slice). Wave tile 64x128 = rt4 x jt8, two jiter passes.
// ============================================================================
__global__ __launch_bounds__(256, 2) void k_score(
    const ushort_t* __restrict__ s1p, const ushort_t* __restrict__ s2p,
    float4* __restrict__ part)
{
    __shared__ float4 mrg[128][2];

    const int bx = blockIdx.x;
    const int b = bx & 7, rt16 = (bx >> 3) & 15, jq = bx >> 7;
    const int t = threadIdx.x, w = t >> 6, l = t & 63;
    const int rh = w >> 1, jw = w & 1;
    const int q = l >> 4, n = l & 15;

    mrg[t >> 1][t & 1] = make_float4(-INFINITY, -INFINITY, __int_as_float(0), 0.f);
    __syncthreads();

    // this wave's 4 A tiles (64 rows), per-lane fragment base
    const ushort_t* Aw = s1p + (size_t)(b * 128 + rt16 * 8 + rh * 4) * 8192 + l * 8;

    f32x4 acc[4][8];

    for (int jiter = 0; jiter < 2; ++jiter) {
        // this wave's 8 B tiles (128 j), per-lane fragment base
        const ushort_t* Bw = s2p + (size_t)(b * 128 + jq * 32 + jiter * 16 + jw * 8) * 8192 + l * 8;

#pragma unroll
        for (int rtl = 0; rtl < 4; ++rtl)
#pragma unroll
            for (int jt = 0; jt < 8; ++jt)
#pragma unroll
                for (int r = 0; r < 4; ++r) acc[rtl][jt][r] = 0.f;

#pragma unroll 1
        for (int g = 0; g < 8; ++g) {
            const ushort_t* Ag = Aw + g * 1024;
            const ushort_t* Bg = Bw + g * 1024;
            bf16x8 aF[4][2];
#pragma unroll
            for (int rtl = 0; rtl < 4; ++rtl) {
                aF[rtl][0] = *(const bf16x8*)(Ag + (size_t)rtl * 8192);
                aF[rtl][1] = *(const bf16x8*)(Ag + (size_t)rtl * 8192 + 512);
            }
#pragma unroll
            for (int jt = 0; jt < 8; ++jt) {
                bf16x8 bh = *(const bf16x8*)(Bg + (size_t)jt * 8192);
                bf16x8 bl = *(const bf16x8*)(Bg + (size_t)jt * 8192 + 512);
#pragma unroll
                for (int rtl = 0; rtl < 4; ++rtl) {
                    acc[rtl][jt] = __builtin_amdgcn_mfma_f32_16x16x32_bf16(aF[rtl][0], bh, acc[rtl][jt], 0, 0, 0);
                    acc[rtl][jt] = __builtin_amdgcn_mfma_f32_16x16x32_bf16(aF[rtl][0], bl, acc[rtl][jt], 0, 0, 0);
                    acc[rtl][jt] = __builtin_amdgcn_mfma_f32_16x16x32_bf16(aF[rtl][1], bh, acc[rtl][jt], 0, 0, 0);
                }
            }
        }

        // top-2 per row over this jiter's 128 j handled by this wave
#pragma unroll
        for (int rtl = 0; rtl < 4; ++rtl)
#pragma unroll
            for (int reg = 0; reg < 4; ++reg) {
                float v1 = -INFINITY, v2 = -INFINITY; int i1 = 0;
#pragma unroll
                for (int jt = 0; jt < 8; ++jt) {
                    float v = acc[rtl][jt][reg];
                    int j = jq * 512 + jiter * 256 + jw * 128 + jt * 16 + n;  // ascending in jt
                    if (v > v1)      { v2 = v1; v1 = v; i1 = j; }
                    else if (v > v2) { v2 = v; }
                }
#pragma unroll
                for (int off = 1; off < 16; off <<= 1) {
                    float b1 = __shfl_xor(v1, off);
                    int   bi = __shfl_xor(i1, off);
                    float b2 = __shfl_xor(v2, off);
                    if (b1 > v1 || (b1 == v1 && bi < i1)) { v2 = fmaxf(v1, b2); v1 = b1; i1 = bi; }
                    else                                   { v2 = fmaxf(b1, v2); }
                }
                int rr = rtl * 4 + reg;
                if (n == rr) {   // 4 active lanes (one per quad), distinct rows
                    int row = rh * 64 + rtl * 16 + q * 4 + reg;
                    float4 cur = mrg[row][jw];
                    int ci = __float_as_int(cur.z);
                    if (v1 > cur.x || (v1 == cur.x && i1 < ci))
                        mrg[row][jw] = make_float4(v1, fmaxf(v2, cur.x), __int_as_float(i1), 0.f);
                    else
                        mrg[row][jw] = make_float4(cur.x, fmaxf(cur.y, v1), cur.z, 0.f);
                }
            }
    }

    __syncthreads();
    if (t < 128) {
        float4 p0 = mrg[t][0], p1 = mrg[t][1];
        int i0 = __float_as_int(p0.z), i1 = __float_as_int(p1.z);
        float v1, v2; int ii;
        if (p1.x > p0.x || (p1.x == p0.x && i1 < i0)) { v1 = p1.x; v2 = fmaxf(p1.y, p0.x); ii = i1; }
        else                                          { v1 = p0.x; v2 = fmaxf(p0.y, p1.x); ii = i0; }
        part[((size_t)b * 2048 + rt16 * 128 + t) * 4 + jq] =
            make_float4(v1, v2, __int_as_float(ii), 0.f);
    }
}

// ============================================================================
// K2: merge 4 j-quarter partials per row, flag near-ties, write one-hot + u.
// 2048 blocks x 256 thr, 8 rows per block. Pure streaming stores (HBM-bound).
// ============================================================================
__global__ __launch_bounds__(256) void k_epilogue(
    const float* __restrict__ s2, const float4* __restrict__ part,
    float* __restrict__ u, float* __restrict__ oh,
    int* __restrict__ qcount, int* __restrict__ queue)
{
    __shared__ int idxs[8];
    const int blk = blockIdx.x, t = threadIdx.x;
    const int r0 = blk * 8;
    const int b = r0 >> 11;
    if (t < 32) {
        int rl = t >> 2, p = t & 3;
        float4 pa = part[(size_t)(r0 + rl) * 4 + p];
        float v1 = pa.x, v2 = pa.y; int i1 = __float_as_int(pa.z);
#pragma unroll
        for (int off = 1; off < 4; off <<= 1) {
            float b1 = __shfl_xor(v1, off);
            int   bi = __shfl_xor(i1, off);
            float b2 = __shfl_xor(v2, off);
            if (b1 > v1 || (b1 == v1 && bi < i1)) { v2 = fmaxf(v1, b2); v1 = b1; i1 = bi; }
            else                                   { v2 = fmaxf(b1, v2); }
        }
        if (p == 0) {
            idxs[rl] = i1;
            if ((v1 - v2) < MARGIN) {
                int pos = atomicAdd(qcount, 1);
                if (pos < 16384) queue[pos] = r0 + rl;
            }
        }
    }
    __syncthreads();
    const float* s2b = s2 + (size_t)b * T2 * D;
    float* ub = u + (size_t)r0 * D;
#pragma unroll
    for (int i = 0; i < 2; ++i) {
        int flat = i * 256 + t, rl = flat >> 6, c = flat & 63;
        float4 v = *(const float4*)(s2b + (size_t)idxs[rl] * D + c * 4);
        *(float4*)(ub + (size_t)rl * D + c * 4) = v;
    }
    float* ohb = oh + (size_t)r0 * T2;
#pragma unroll 4
    for (int i = 0; i < 16; ++i) {
        int flat = i * 256 + t, rl = flat >> 9, c4 = flat & 511;
        int base = c4 * 4, id = idxs[rl];
        float4 vv;
        vv.x = (base     == id) ? 1.f : 0.f;
        vv.y = (base + 1 == id) ? 1.f : 0.f;
        vv.z = (base + 2 == id) ? 1.f : 0.f;
        vv.w = (base + 3 == id) ? 1.f : 0.f;
        *(float4*)(ohb + (size_t)rl * T2 + base) = vv;
    }
}

// ============================================================================
// K3: exact float64 recompute for flagged (near-tie) rows.
// ============================================================================
__global__ __launch_bounds__(256) void k_fixup(
    const float* __restrict__ s1, const float* __restrict__ s2,
    float* __restrict__ u, float* __restrict__ oh,
    const int* __restrict__ qcount, const int* __restrict__ queue, int qcap)
{
    __shared__ double s1d[D];
    __shared__ double rv[256];
    __shared__ int    rj[256];
    int nq = *qcount;
    if (nq > qcap) nq = qcap;
    const int t = threadIdx.x;
    for (int qi = blockIdx.x; qi < nq; qi += gridDim.x) {
        int rg = queue[qi];
        int b = rg >> 11, i = rg & (T1 - 1);
        __syncthreads();
        s1d[t] = (double)s1[((size_t)b * T1 + i) * D + t];
        __syncthreads();
        double bv = -INFINITY; int bj = 0;
        for (int jj = 0; jj < T2 / 256; ++jj) {
            int j = t + jj * 256;
            const float* row = s2 + ((size_t)b * T2 + j) * D;
            double s = 0.0;
            for (int k = 0; k < D; ++k) s = fma((double)row[k], s1d[k], s);
            if (s > bv) { bv = s; bj = j; }
        }
        rv[t] = bv; rj[t] = bj;
        __syncthreads();
        for (int stride = 128; stride > 0; stride >>= 1) {
            if (t < stride) {
                double ov = rv[t + stride]; int oj = rj[t + stride];
                if (ov > rv[t] || (ov == rv[t] && oj < rj[t])) { rv[t] = ov; rj[t] = oj; }
            }
            __syncthreads();
        }
        int best = rj[0];
        float* ohrow = oh + ((size_t)b * T1 + i) * T2;
#pragma unroll
        for (int jj = 0; jj < T2 / 256; ++jj) {
            int j = t + jj * 256;
            ohrow[j] = (j == best) ? 1.f : 0.f;
        }
        u[((size_t)b * T1 + i) * D + t] = s2[((size_t)b * T2 + best) * D + t];
    }
}

// ============================================================================
// Fallback (ws too small): round-2 fused kernel, verified correct.
// ============================================================================
constexpr int FB_AST = 264, FB_BST = 72;

__global__ __launch_bounds__(512, 2) void k_score_fb(
    const float* __restrict__ s1, const float* __restrict__ s2,
    float* __restrict__ u, float* __restrict__ oh,
    int* __restrict__ qcount, int* __restrict__ queue, int qcap)
{
    __shared__ __align__(16) short Ah[64 * FB_AST];
    __shared__ __align__(16) short Al[64 * FB_AST];
    __shared__ __align__(16) short Bh[256 * FB_BST];
    __shared__ __align__(16) short Bl[256 * FB_BST];
    __shared__ float cv1[64][4], cv2[64][4];
    __shared__ int   ci1[64][4], idx_s[64];

    const int bx = blockIdx.x;
    const int b  = bx & 7;
    const int r0 = (bx >> 3) * 64;
    const float* s1b = s1 + ((size_t)b * T1 + r0) * D;
    const float* s2b = s2 + (size_t)b * T2 * D;

    const int t = threadIdx.x;
    const int w = t >> 6, l = t & 63, q = l >> 4, ln = l & 15;
    const int rh = w >> 2;
    const int jq = w & 3;

    float4 pa[8];
#pragma unroll
    for (int i = 0; i < 8; ++i) {
        int flat = i * 512 + t, row = flat >> 6, f4 = flat & 63;
        pa[i] = *(const float4*)(s1b + row * D + f4 * 4);
    }
    float4 pb[8];
#pragma unroll
    for (int i = 0; i < 8; ++i) {
        int flat = i * 512 + t, jrow = flat >> 4, f4 = flat & 15;
        pb[i] = *(const float4*)(s2b + (size_t)jrow * D + f4 * 4);
    }
#pragma unroll
    for (int i = 0; i < 8; ++i) {
        int flat = i * 512 + t, row = flat >> 6, f4 = flat & 63;
        float4 v = pa[i];
        unsigned hx = f2bf(v.x), hy = f2bf(v.y), hz = f2bf(v.z), hw = f2bf(v.w);
        uint2 hh, ll;
        hh.x = hx | (hy << 16); hh.y = hz | (hw << 16);
        ll.x = f2bf(v.x - bf2f(hx)) | (f2bf(v.y - bf2f(hy)) << 16);
        ll.y = f2bf(v.z - bf2f(hz)) | (f2bf(v.w - bf2f(hw)) << 16);
        *(uint2*)(&Ah[row * FB_AST + f4 * 4]) = hh;
        *(uint2*)(&Al[row * FB_AST + f4 * 4]) = ll;
    }

    float v1[2][4], v2[2][4]; int i1[2][4];
#pragma unroll
    for (int rt = 0; rt < 2; ++rt)
#pragma unroll
        for (int r = 0; r < 4; ++r) { v1[rt][r] = -INFINITY; v2[rt][r] = -INFINITY; i1[rt][r] = 0; }

    f32x4 acc[2][4];

    for (int c = 0; c < 32; ++c) {
        const int iter = c >> 2, kc = c & 3;
        if (kc == 0) {
#pragma unroll
            for (int rt = 0; rt < 2; ++rt)
#pragma unroll
                for (int jt = 0; jt < 4; ++jt)
#pragma unroll
                    for (int r = 0; r < 4; ++r) acc[rt][jt][r] = 0.f;
        }
        __syncthreads();
#pragma unroll
        for (int i = 0; i < 8; ++i) {
            int flat = i * 512 + t, jrow = flat >> 4, f4 = flat & 15;
            float4 v = pb[i];
            unsigned hx = f2bf(v.x), hy = f2bf(v.y), hz = f2bf(v.z), hw = f2bf(v.w);
            uint2 hh, ll;
            hh.x = hx | (hy << 16); hh.y = hz | (hw << 16);
            ll.x = f2bf(v.x - bf2f(hx)) | (f2bf(v.y - bf2f(hy)) << 16);
            ll.y = f2bf(v.z - bf2f(hz)) | (f2bf(v.w - bf2f(hw)) << 16);
            *(uint2*)(&Bh[jrow * FB_BST + f4 * 4]) = hh;
            *(uint2*)(&Bl[jrow * FB_BST + f4 * 4]) = ll;
        }
        if (c < 31) {
            int c2 = c + 1, it2 = c2 >> 2, kc2 = c2 & 3;
#pragma unroll
            for (int i = 0; i < 8; ++i) {
                int flat = i * 512 + t, jrow = flat >> 4, f4 = flat & 15;
                pb[i] = *(const float4*)(s2b + (size_t)(it2 * 256 + jrow) * D + kc2 * 64 + f4 * 4);
            }
        }
        __syncthreads();

#pragma unroll
        for (int ks = 0; ks < 2; ++ks) {
            const int kA = kc * 64 + ks * 32 + q * 8;
            bf16x8 ah[2], al8[2];
#pragma unroll
            for (int rt = 0; rt < 2; ++rt) {
                int off = (rh * 32 + rt * 16 + ln) * FB_AST + kA;
                ah[rt]  = *(const bf16x8*)(&Ah[off]);
                al8[rt] = *(const bf16x8*)(&Al[off]);
            }
#pragma unroll
            for (int jt = 0; jt < 4; ++jt) {
                int boff = (jq * 64 + jt * 16 + ln) * FB_BST + ks * 32 + q * 8;
                bf16x8 bh = *(const bf16x8*)(&Bh[boff]);
                bf16x8 bl = *(const bf16x8*)(&Bl[boff]);
#pragma unroll
                for (int rt = 0; rt < 2; ++rt) {
                    acc[rt][jt] = __builtin_amdgcn_mfma_f32_16x16x32_bf16(ah[rt],  bh, acc[rt][jt], 0, 0, 0);
                    acc[rt][jt] = __builtin_amdgcn_mfma_f32_16x16x32_bf16(ah[rt],  bl, acc[rt][jt], 0, 0, 0);
                    acc[rt][jt] = __builtin_amdgcn_mfma_f32_16x16x32_bf16(al8[rt], bh, acc[rt][jt], 0, 0, 0);
                }
            }
        }

        if (kc == 3) {
#pragma unroll
            for (int rt = 0; rt < 2; ++rt)
#pragma unroll
                for (int jt = 0; jt < 4; ++jt)
#pragma unroll
                    for (int r = 0; r < 4; ++r) {
                        float val = acc[rt][jt][r];
                        int j = iter * 256 + jq * 64 + jt * 16 + ln;
                        if (val > v1[rt][r]) { v2[rt][r] = v1[rt][r]; v1[rt][r] = val; i1[rt][r] = j; }
                        else if (val > v2[rt][r]) v2[rt][r] = val;
                    }
        }
    }

#pragma unroll
    for (int rt = 0; rt < 2; ++rt)
#pragma unroll
        for (int r = 0; r < 4; ++r) {
            float a1 = v1[rt][r], a2 = v2[rt][r]; int ai = i1[rt][r];
#pragma unroll
            for (int off = 1; off < 16; off <<= 1) {
                float b1 = __shfl_xor(a1, off);
                int   bi = __shfl_xor(ai, off);
                float b2 = __shfl_xor(a2, off);
                if (b1 > a1 || (b1 == a1 && bi < ai)) { a2 = fmaxf(a1, b2); a1 = b1; ai = bi; }
                else                                   { a2 = fmaxf(b1, a2); }
            }
            if (ln == 0) {
                int row = rh * 32 + rt * 16 + q * 4 + r;
                cv1[row][jq] = a1; cv2[row][jq] = a2; ci1[row][jq] = ai;
            }
        }
    __syncthreads();

    if (t < 64) {
        float V1 = cv1[t][0], V2 = cv2[t][0]; int I = ci1[t][0];
#pragma unroll
        for (int h = 1; h < 4; ++h) {
            float c1 = cv1[t][h], c2 = cv2[t][h]; int ci = ci1[t][h];
            if (c1 > V1 || (c1 == V1 && ci < I)) { V2 = fmaxf(V1, c2); V1 = c1; I = ci; }
            else                                  { V2 = fmaxf(V2, c1); }
        }
        idx_s[t] = I;
        if (qcap > 0 && (V1 - V2) < MARGIN) {
            int pos = atomicAdd(qcount, 1);
            if (pos < qcap) queue[pos] = b * T1 + r0 + t;
        }
    }
    __syncthreads();

    float* ub = u + ((size_t)b * T1 + r0) * D;
#pragma unroll
    for (int i = 0; i < 8; ++i) {
        int flat = i * 512 + t, row = flat >> 6, f4 = flat & 63;
        float4 v = *(const float4*)(s2b + (size_t)idx_s[row] * D + f4 * 4);
        *(float4*)(ub + (size_t)row * D + f4 * 4) = v;
    }
    float* ohb = oh + ((size_t)b * T1 + r0) * T2;
#pragma unroll 4
    for (int i = 0; i < 64; ++i) {
        int flat = i * 512 + t, row = flat >> 9, f4 = flat & 511;
        int base = f4 * 4, id = idx_s[row];
        float4 vv;
        vv.x = (base     == id) ? 1.f : 0.f;
        vv.y = (base + 1 == id) ? 1.f : 0.f;
        vv.z = (base + 2 == id) ? 1.f : 0.f;
        vv.w = (base + 3 == id) ? 1.f : 0.f;
        *(float4*)(ohb + (size_t)row * T2 + base) = vv;
    }
}

extern "C" void kernel_launch(void* const* d_in, const int* in_sizes, int n_in,
                              void* d_out, int out_size, void* d_ws, size_t ws_size,
                              hipStream_t stream)
{
    const float* s1 = (const float*)d_in[0];
    const float* s2 = (const float*)d_in[1];
    float* u  = (float*)d_out;                       // [8,2048,256]
    float* oh = u + (size_t)BB * T1 * D;             // [8,2048,2048]
    char* ws = (char*)d_ws;

    if (ws_size >= WS_NEEDED) {
        int*      qc    = (int*)(ws + OFF_QC);
        int*      queue = (int*)(ws + OFF_QUEUE);
        float4*   part  = (float4*)(ws + OFF_PART);
        ushort_t* s1p   = (ushort_t*)(ws + OFF_S1P);
        ushort_t* s2p   = (ushort_t*)(ws + OFF_S2P);
        hipMemsetAsync(ws + OFF_QC, 0, 16, stream);
        k_convert<<<dim3(1024), dim3(256), 0, stream>>>(s1, s2, s1p, s2p);
        k_score<<<dim3(512), dim3(256), 0, stream>>>(s1p, s2p, part);
        k_epilogue<<<dim3(2048), dim3(256), 0, stream>>>(s2, part, u, oh, qc, queue);
        k_fixup<<<dim3(128), dim3(256), 0, stream>>>(s1, s2, u, oh, qc, queue, 16384);
    } else {
        int  qcap   = 0;
        int* qcount = nullptr;
        int* queue  = nullptr;
        if (ws_size >= 256) {
            qcount = (int*)d_ws;
            queue  = (int*)d_ws + 4;
            size_t cap = (ws_size - 16) / sizeof(int);
            qcap = (int)(cap > (size_t)(BB * T1) ? (size_t)(BB * T1) : cap);
            hipMemsetAsync(d_ws, 0, 16, stream);
        }
        k_score_fb<<<dim3(BB * (T1 / 64)), dim3(512), 0, stream>>>(
            s1, s2, u, oh, qcount, queue, qcap);
        if (qcap > 0)
            k_fixup<<<dim3(64), dim3(256), 0, stream>>>(
                s1, s2, u, oh, qcount, queue, qcap);
    }
}

// Round 6
// 304.901 us; speedup vs baseline: 2.2351x; 1.0067x over previous
//
#include <hip/hip_runtime.h>
#include <math.h>

typedef unsigned short ushort_t;

constexpr int BB = 8, T1 = 2048, T2 = 2048, D = 256;
constexpr float MARGIN = 4e-3f;   // 3-limb bf16 score error ~1e-4; 40x headroom

// ---- workspace layout (fast path) ----
constexpr size_t OFF_QC    = 0;                         // int counter (16 B)
constexpr size_t OFF_QUEUE = 64;                        // 16384 ints
constexpr size_t OFF_PART  = (size_t)1 << 20;           // float4[16384*16] = 4 MB
constexpr size_t OFF_S1P   = (size_t)6 << 20;           // packed bf16 hi/lo s1 (16.8 MB)
constexpr size_t SZ_PACK   = (size_t)BB * 128 * 8 * 2 * 64 * 16; // b*tile16*g*limb*lane*16B
constexpr size_t OFF_S2P   = OFF_S1P + SZ_PACK;
constexpr size_t WS_NEEDED = OFF_S2P + SZ_PACK;         // ~39.7 MB

typedef __attribute__((ext_vector_type(8))) __bf16 bf16x8;
typedef __attribute__((ext_vector_type(4))) float  f32x4;

__device__ __forceinline__ unsigned f2bf(float x) {
    unsigned u = __float_as_uint(x);
    return (u + 0x7fffu + ((u >> 16) & 1u)) >> 16;
}
__device__ __forceinline__ float bf2f(unsigned h) { return __uint_as_float(h << 16); }

// ============================================================================
// K0: convert fp32 -> bf16 hi/lo, packed in MFMA-fragment tile order.
// Tile = 16 rows x 32 k. Chunk (1 KB) = [lane 0..63][8 shorts],
// lane = (row&15) + 16*((k&31)>>3), element i -> k = (lane>>4)*8 + i.
// Flat: [b][tile16 (128)][g (8)][limb (2)][lane (64)][16 B].
// ============================================================================
__global__ __launch_bounds__(256) void k_convert(
    const float* __restrict__ s1, const float* __restrict__ s2,
    ushort_t* __restrict__ s1p, ushort_t* __restrict__ s2p)
{
    __shared__ __align__(16) ushort_t L[16384];   // 32 KB staging (2 tile16 of output)
    const int bx = blockIdx.x;
    const int tensor = bx >> 9, b = (bx >> 6) & 7, rt = bx & 63;  // rt: 32-row group
    const float* src = (tensor ? s2 : s1) + ((size_t)b * 2048 + rt * 32) * 256;
    ushort_t* dst = (tensor ? s2p : s1p) + (size_t)(b * 128 + rt * 2) * 8192;
    const int t = threadIdx.x;
#pragma unroll
    for (int i = 0; i < 8; ++i) {
        int f = i * 256 + t, rw = f >> 6, c4 = f & 63, k0 = c4 * 4;
        float4 v = *(const float4*)(src + rw * 256 + k0);
        unsigned hx = f2bf(v.x), hy = f2bf(v.y), hz = f2bf(v.z), hw = f2bf(v.w);
        ushort4 hi = make_ushort4((ushort_t)hx, (ushort_t)hy, (ushort_t)hz, (ushort_t)hw);
        ushort4 lo = make_ushort4((ushort_t)f2bf(v.x - bf2f(hx)), (ushort_t)f2bf(v.y - bf2f(hy)),
                                  (ushort_t)f2bf(v.z - bf2f(hz)), (ushort_t)f2bf(v.w - bf2f(hw)));
        int tile = rw >> 4, m = rw & 15, g = k0 >> 5;
        int lane = m + 16 * ((k0 >> 3) & 3), i0 = k0 & 7;
        int off = (tile * 8 + g) * 1024 + lane * 8 + i0;   // limb stride 512 shorts
        *(ushort4*)(&L[off])       = hi;
        *(ushort4*)(&L[off + 512]) = lo;
    }
    __syncthreads();
#pragma unroll
    for (int i = 0; i < 8; ++i) {
        int cidx = i * 256 + t;                             // 2048 x 16 B = 32 KB
        ((uint4*)dst)[cidx] = ((const uint4*)L)[cidx];
    }
}

// ============================================================================
// K1 (r6): barrier-free direct-global score, 64x64 wave tile for occupancy.
// r5 post-mortem: acc[4][8]=128 VGPR forced 2 waves/SIMD -> L3 latency
// (~600 cyc) unhidden before each MFMA burst. r6: acc[4][4]=64 VGPR,
// __launch_bounds__(256,3) -> 12 waves/CU, grid 512->2048 blocks.
// Grid 2048: b=bx&7, rt16=(bx>>3)&15 (128 rows), jq=bx>>7 (0..15, 128 j).
// Block 256 thr = 4 waves: rh=w>>1 (64-row half), jw=w&1 (64-j half).
// Wave tile 64x64 = rt4 x jt4 of verified 16x16x32 bf16 tiles, 3-limb.
// ============================================================================
__global__ __launch_bounds__(256, 3) void k_score(
    const ushort_t* __restrict__ s1p, const ushort_t* __restrict__ s2p,
    float4* __restrict__ part)
{
    __shared__ float4 mrg[128][2];

    const int bx = blockIdx.x;
    const int b = bx & 7, rt16 = (bx >> 3) & 15, jq = bx >> 7;
    const int t = threadIdx.x, w = t >> 6, l = t & 63;
    const int rh = w >> 1, jw = w & 1;
    const int q = l >> 4, n = l & 15;

    mrg[t >> 1][t & 1] = make_float4(-INFINITY, -INFINITY, __int_as_float(0), 0.f);
    __syncthreads();

    // per-lane fragment bases (packed layout == exact MFMA lane order)
    const ushort_t* Aw = s1p + (size_t)(b * 128 + rt16 * 8 + rh * 4) * 8192 + l * 8;
    const ushort_t* Bw = s2p + (size_t)(b * 128 + jq * 8 + jw * 4) * 8192 + l * 8;

    f32x4 acc[4][4];
#pragma unroll
    for (int rtl = 0; rtl < 4; ++rtl)
#pragma unroll
        for (int jt = 0; jt < 4; ++jt)
#pragma unroll
            for (int r = 0; r < 4; ++r) acc[rtl][jt][r] = 0.f;

#pragma unroll 1
    for (int g = 0; g < 8; ++g) {
        const ushort_t* Ag = Aw + g * 1024;
        const ushort_t* Bg = Bw + g * 1024;
        bf16x8 aF[4][2];
#pragma unroll
        for (int rtl = 0; rtl < 4; ++rtl) {
            aF[rtl][0] = *(const bf16x8*)(Ag + (size_t)rtl * 8192);
            aF[rtl][1] = *(const bf16x8*)(Ag + (size_t)rtl * 8192 + 512);
        }
#pragma unroll
        for (int jt = 0; jt < 4; ++jt) {
            bf16x8 bh = *(const bf16x8*)(Bg + (size_t)jt * 8192);
            bf16x8 bl = *(const bf16x8*)(Bg + (size_t)jt * 8192 + 512);
#pragma unroll
            for (int rtl = 0; rtl < 4; ++rtl) {
                acc[rtl][jt] = __builtin_amdgcn_mfma_f32_16x16x32_bf16(aF[rtl][0], bh, acc[rtl][jt], 0, 0, 0);
                acc[rtl][jt] = __builtin_amdgcn_mfma_f32_16x16x32_bf16(aF[rtl][0], bl, acc[rtl][jt], 0, 0, 0);
                acc[rtl][jt] = __builtin_amdgcn_mfma_f32_16x16x32_bf16(aF[rtl][1], bh, acc[rtl][jt], 0, 0, 0);
            }
        }
    }

    // top-2 per row over this wave's 64 j
#pragma unroll
    for (int rtl = 0; rtl < 4; ++rtl)
#pragma unroll
        for (int reg = 0; reg < 4; ++reg) {
            float v1 = -INFINITY, v2 = -INFINITY; int i1 = 0;
#pragma unroll
            for (int jt = 0; jt < 4; ++jt) {
                float v = acc[rtl][jt][reg];
                int j = jq * 128 + jw * 64 + jt * 16 + n;   // ascending in jt
                if (v > v1)      { v2 = v1; v1 = v; i1 = j; }
                else if (v > v2) { v2 = v; }
            }
#pragma unroll
            for (int off = 1; off < 16; off <<= 1) {
                float b1 = __shfl_xor(v1, off);
                int   bi = __shfl_xor(i1, off);
                float b2 = __shfl_xor(v2, off);
                if (b1 > v1 || (b1 == v1 && bi < i1)) { v2 = fmaxf(v1, b2); v1 = b1; i1 = bi; }
                else                                   { v2 = fmaxf(b1, v2); }
            }
            int rr = rtl * 4 + reg;
            if (n == rr) {   // 4 active lanes (one per quad), distinct rows
                int row = rh * 64 + rtl * 16 + q * 4 + reg;
                float4 cur = mrg[row][jw];
                int ci = __float_as_int(cur.z);
                if (v1 > cur.x || (v1 == cur.x && i1 < ci))
                    mrg[row][jw] = make_float4(v1, fmaxf(v2, cur.x), __int_as_float(i1), 0.f);
                else
                    mrg[row][jw] = make_float4(cur.x, fmaxf(cur.y, v1), cur.z, 0.f);
            }
        }

    __syncthreads();
    if (t < 128) {
        float4 p0 = mrg[t][0], p1 = mrg[t][1];
        int i0 = __float_as_int(p0.z), i1 = __float_as_int(p1.z);
        float v1, v2; int ii;
        if (p1.x > p0.x || (p1.x == p0.x && i1 < i0)) { v1 = p1.x; v2 = fmaxf(p1.y, p0.x); ii = i1; }
        else                                          { v1 = p0.x; v2 = fmaxf(p0.y, p1.x); ii = i0; }
        part[((size_t)b * 2048 + rt16 * 128 + t) * 16 + jq] =
            make_float4(v1, v2, __int_as_float(ii), 0.f);
    }
}

// ============================================================================
// K2: merge 16 j-slice partials per row, flag near-ties, write one-hot + u.
// 2048 blocks x 256 thr, 8 rows per block. Pure streaming stores (HBM-bound).
// ============================================================================
__global__ __launch_bounds__(256) void k_epilogue(
    const float* __restrict__ s2, const float4* __restrict__ part,
    float* __restrict__ u, float* __restrict__ oh,
    int* __restrict__ qcount, int* __restrict__ queue)
{
    __shared__ int idxs[8];
    const int blk = blockIdx.x, t = threadIdx.x;
    const int r0 = blk * 8;
    const int b = r0 >> 11;
    if (t < 128) {
        int rl = t >> 4, p = t & 15;
        float4 pa = part[(size_t)(r0 + rl) * 16 + p];
        float v1 = pa.x, v2 = pa.y; int i1 = __float_as_int(pa.z);
#pragma unroll
        for (int off = 1; off < 16; off <<= 1) {
            float b1 = __shfl_xor(v1, off);
            int   bi = __shfl_xor(i1, off);
            float b2 = __shfl_xor(v2, off);
            if (b1 > v1 || (b1 == v1 && bi < i1)) { v2 = fmaxf(v1, b2); v1 = b1; i1 = bi; }
            else                                   { v2 = fmaxf(b1, v2); }
        }
        if (p == 0) {
            idxs[rl] = i1;
            if ((v1 - v2) < MARGIN) {
                int pos = atomicAdd(qcount, 1);
                if (pos < 16384) queue[pos] = r0 + rl;
            }
        }
    }
    __syncthreads();
    const float* s2b = s2 + (size_t)b * T2 * D;
    float* ub = u + (size_t)r0 * D;
#pragma unroll
    for (int i = 0; i < 2; ++i) {
        int flat = i * 256 + t, rl = flat >> 6, c = flat & 63;
        float4 v = *(const float4*)(s2b + (size_t)idxs[rl] * D + c * 4);
        *(float4*)(ub + (size_t)rl * D + c * 4) = v;
    }
    float* ohb = oh + (size_t)r0 * T2;
#pragma unroll 4
    for (int i = 0; i < 16; ++i) {
        int flat = i * 256 + t, rl = flat >> 9, c4 = flat & 511;
        int base = c4 * 4, id = idxs[rl];
        float4 vv;
        vv.x = (base     == id) ? 1.f : 0.f;
        vv.y = (base + 1 == id) ? 1.f : 0.f;
        vv.z = (base + 2 == id) ? 1.f : 0.f;
        vv.w = (base + 3 == id) ? 1.f : 0.f;
        *(float4*)(ohb + (size_t)rl * T2 + base) = vv;
    }
}

// ============================================================================
// K3: exact float64 recompute for flagged (near-tie) rows.
// ============================================================================
__global__ __launch_bounds__(256) void k_fixup(
    const float* __restrict__ s1, const float* __restrict__ s2,
    float* __restrict__ u, float* __restrict__ oh,
    const int* __restrict__ qcount, const int* __restrict__ queue, int qcap)
{
    __shared__ double s1d[D];
    __shared__ double rv[256];
    __shared__ int    rj[256];
    int nq = *qcount;
    if (nq > qcap) nq = qcap;
    const int t = threadIdx.x;
    for (int qi = blockIdx.x; qi < nq; qi += gridDim.x) {
        int rg = queue[qi];
        int b = rg >> 11, i = rg & (T1 - 1);
        __syncthreads();
        s1d[t] = (double)s1[((size_t)b * T1 + i) * D + t];
        __syncthreads();
        double bv = -INFINITY; int bj = 0;
        for (int jj = 0; jj < T2 / 256; ++jj) {
            int j = t + jj * 256;
            const float* row = s2 + ((size_t)b * T2 + j) * D;
            double s = 0.0;
            for (int k = 0; k < D; ++k) s = fma((double)row[k], s1d[k], s);
            if (s > bv) { bv = s; bj = j; }
        }
        rv[t] = bv; rj[t] = bj;
        __syncthreads();
        for (int stride = 128; stride > 0; stride >>= 1) {
            if (t < stride) {
                double ov = rv[t + stride]; int oj = rj[t + stride];
                if (ov > rv[t] || (ov == rv[t] && oj < rj[t])) { rv[t] = ov; rj[t] = oj; }
            }
            __syncthreads();
        }
        int best = rj[0];
        float* ohrow = oh + ((size_t)b * T1 + i) * T2;
#pragma unroll
        for (int jj = 0; jj < T2 / 256; ++jj) {
            int j = t + jj * 256;
            ohrow[j] = (j == best) ? 1.f : 0.f;
        }
        u[((size_t)b * T1 + i) * D + t] = s2[((size_t)b * T2 + best) * D + t];
    }
}

// ============================================================================
// Fallback (ws too small): round-2 fused kernel, verified correct.
// ============================================================================
constexpr int FB_AST = 264, FB_BST = 72;

__global__ __launch_bounds__(512, 2) void k_score_fb(
    const float* __restrict__ s1, const float* __restrict__ s2,
    float* __restrict__ u, float* __restrict__ oh,
    int* __restrict__ qcount, int* __restrict__ queue, int qcap)
{
    __shared__ __align__(16) short Ah[64 * FB_AST];
    __shared__ __align__(16) short Al[64 * FB_AST];
    __shared__ __align__(16) short Bh[256 * FB_BST];
    __shared__ __align__(16) short Bl[256 * FB_BST];
    __shared__ float cv1[64][4], cv2[64][4];
    __shared__ int   ci1[64][4], idx_s[64];

    const int bx = blockIdx.x;
    const int b  = bx & 7;
    const int r0 = (bx >> 3) * 64;
    const float* s1b = s1 + ((size_t)b * T1 + r0) * D;
    const float* s2b = s2 + (size_t)b * T2 * D;

    const int t = threadIdx.x;
    const int w = t >> 6, l = t & 63, q = l >> 4, ln = l & 15;
    const int rh = w >> 2;
    const int jq = w & 3;

    float4 pa[8];
#pragma unroll
    for (int i = 0; i < 8; ++i) {
        int flat = i * 512 + t, row = flat >> 6, f4 = flat & 63;
        pa[i] = *(const float4*)(s1b + row * D + f4 * 4);
    }
    float4 pb[8];
#pragma unroll
    for (int i = 0; i < 8; ++i) {
        int flat = i * 512 + t, jrow = flat >> 4, f4 = flat & 15;
        pb[i] = *(const float4*)(s2b + (size_t)jrow * D + f4 * 4);
    }
#pragma unroll
    for (int i = 0; i < 8; ++i) {
        int flat = i * 512 + t, row = flat >> 6, f4 = flat & 63;
        float4 v = pa[i];
        unsigned hx = f2bf(v.x), hy = f2bf(v.y), hz = f2bf(v.z), hw = f2bf(v.w);
        uint2 hh, ll;
        hh.x = hx | (hy << 16); hh.y = hz | (hw << 16);
        ll.x = f2bf(v.x - bf2f(hx)) | (f2bf(v.y - bf2f(hy)) << 16);
        ll.y = f2bf(v.z - bf2f(hz)) | (f2bf(v.w - bf2f(hw)) << 16);
        *(uint2*)(&Ah[row * FB_AST + f4 * 4]) = hh;
        *(uint2*)(&Al[row * FB_AST + f4 * 4]) = ll;
    }

    float v1[2][4], v2[2][4]; int i1[2][4];
#pragma unroll
    for (int rt = 0; rt < 2; ++rt)
#pragma unroll
        for (int r = 0; r < 4; ++r) { v1[rt][r] = -INFINITY; v2[rt][r] = -INFINITY; i1[rt][r] = 0; }

    f32x4 acc[2][4];

    for (int c = 0; c < 32; ++c) {
        const int iter = c >> 2, kc = c & 3;
        if (kc == 0) {
#pragma unroll
            for (int rt = 0; rt < 2; ++rt)
#pragma unroll
                for (int jt = 0; jt < 4; ++jt)
#pragma unroll
                    for (int r = 0; r < 4; ++r) acc[rt][jt][r] = 0.f;
        }
        __syncthreads();
#pragma unroll
        for (int i = 0; i < 8; ++i) {
            int flat = i * 512 + t, jrow = flat >> 4, f4 = flat & 15;
            float4 v = pb[i];
            unsigned hx = f2bf(v.x), hy = f2bf(v.y), hz = f2bf(v.z), hw = f2bf(v.w);
            uint2 hh, ll;
            hh.x = hx | (hy << 16); hh.y = hz | (hw << 16);
            ll.x = f2bf(v.x - bf2f(hx)) | (f2bf(v.y - bf2f(hy)) << 16);
            ll.y = f2bf(v.z - bf2f(hz)) | (f2bf(v.w - bf2f(hw)) << 16);
            *(uint2*)(&Bh[jrow * FB_BST + f4 * 4]) = hh;
            *(uint2*)(&Bl[jrow * FB_BST + f4 * 4]) = ll;
        }
        if (c < 31) {
            int c2 = c + 1, it2 = c2 >> 2, kc2 = c2 & 3;
#pragma unroll
            for (int i = 0; i < 8; ++i) {
                int flat = i * 512 + t, jrow = flat >> 4, f4 = flat & 15;
                pb[i] = *(const float4*)(s2b + (size_t)(it2 * 256 + jrow) * D + kc2 * 64 + f4 * 4);
            }
        }
        __syncthreads();

#pragma unroll
        for (int ks = 0; ks < 2; ++ks) {
            const int kA = kc * 64 + ks * 32 + q * 8;
            bf16x8 ah[2], al8[2];
#pragma unroll
            for (int rt = 0; rt < 2; ++rt) {
                int off = (rh * 32 + rt * 16 + ln) * FB_AST + kA;
                ah[rt]  = *(const bf16x8*)(&Ah[off]);
                al8[rt] = *(const bf16x8*)(&Al[off]);
            }
#pragma unroll
            for (int jt = 0; jt < 4; ++jt) {
                int boff = (jq * 64 + jt * 16 + ln) * FB_BST + ks * 32 + q * 8;
                bf16x8 bh = *(const bf16x8*)(&Bh[boff]);
                bf16x8 bl = *(const bf16x8*)(&Bl[boff]);
#pragma unroll
                for (int rt = 0; rt < 2; ++rt) {
                    acc[rt][jt] = __builtin_amdgcn_mfma_f32_16x16x32_bf16(ah[rt],  bh, acc[rt][jt], 0, 0, 0);
                    acc[rt][jt] = __builtin_amdgcn_mfma_f32_16x16x32_bf16(ah[rt],  bl, acc[rt][jt], 0, 0, 0);
                    acc[rt][jt] = __builtin_amdgcn_mfma_f32_16x16x32_bf16(al8[rt], bh, acc[rt][jt], 0, 0, 0);
                }
            }
        }

        if (kc == 3) {
#pragma unroll
            for (int rt = 0; rt < 2; ++rt)
#pragma unroll
                for (int jt = 0; jt < 4; ++jt)
#pragma unroll
                    for (int r = 0; r < 4; ++r) {
                        float val = acc[rt][jt][r];
                        int j = iter * 256 + jq * 64 + jt * 16 + ln;
                        if (val > v1[rt][r]) { v2[rt][r] = v1[rt][r]; v1[rt][r] = val; i1[rt][r] = j; }
                        else if (val > v2[rt][r]) v2[rt][r] = val;
                    }
        }
    }

#pragma unroll
    for (int rt = 0; rt < 2; ++rt)
#pragma unroll
        for (int r = 0; r < 4; ++r) {
            float a1 = v1[rt][r], a2 = v2[rt][r]; int ai = i1[rt][r];
#pragma unroll
            for (int off = 1; off < 16; off <<= 1) {
                float b1 = __shfl_xor(a1, off);
                int   bi = __shfl_xor(ai, off);
                float b2 = __shfl_xor(a2, off);
                if (b1 > a1 || (b1 == a1 && bi < ai)) { a2 = fmaxf(a1, b2); a1 = b1; ai = bi; }
                else                                   { a2 = fmaxf(b1, a2); }
            }
            if (ln == 0) {
                int row = rh * 32 + rt * 16 + q * 4 + r;
                cv1[row][jq] = a1; cv2[row][jq] = a2; ci1[row][jq] = ai;
            }
        }
    __syncthreads();

    if (t < 64) {
        float V1 = cv1[t][0], V2 = cv2[t][0]; int I = ci1[t][0];
#pragma unroll
        for (int h = 1; h < 4; ++h) {
            float c1 = cv1[t][h], c2 = cv2[t][h]; int ci = ci1[t][h];
            if (c1 > V1 || (c1 == V1 && ci < I)) { V2 = fmaxf(V1, c2); V1 = c1; I = ci; }
            else                                  { V2 = fmaxf(V2, c1); }
        }
        idx_s[t] = I;
        if (qcap > 0 && (V1 - V2) < MARGIN) {
            int pos = atomicAdd(qcount, 1);
            if (pos < qcap) queue[pos] = b * T1 + r0 + t;
        }
    }
    __syncthreads();

    float* ub = u + ((size_t)b * T1 + r0) * D;
#pragma unroll
    for (int i = 0; i < 8; ++i) {
        int flat = i * 512 + t, row = flat >> 6, f4 = flat & 63;
        float4 v = *(const float4*)(s2b + (size_t)idx_s[row] * D + f4 * 4);
        *(float4*)(ub + (size_t)row * D + f4 * 4) = v;
    }
    float* ohb = oh + ((size_t)b * T1 + r0) * T2;
#pragma unroll 4
    for (int i = 0; i < 64; ++i) {
        int flat = i * 512 + t, row = flat >> 9, f4 = flat & 511;
        int base = f4 * 4, id = idx_s[row];
        float4 vv;
        vv.x = (base     == id) ? 1.f : 0.f;
        vv.y = (base + 1 == id) ? 1.f : 0.f;
        vv.z = (base + 2 == id) ? 1.f : 0.f;
        vv.w = (base + 3 == id) ? 1.f : 0.f;
        *(float4*)(ohb + (size_t)row * T2 + base) = vv;
    }
}

extern "C" void kernel_launch(void* const* d_in, const int* in_sizes, int n_in,
                              void* d_out, int out_size, void* d_ws, size_t ws_size,
                              hipStream_t stream)
{
    const float* s1 = (const float*)d_in[0];
    const float* s2 = (const float*)d_in[1];
    float* u  = (float*)d_out;                       // [8,2048,256]
    float* oh = u + (size_t)BB * T1 * D;             // [8,2048,2048]
    char* ws = (char*)d_ws;

    if (ws_size >= WS_NEEDED) {
        int*      qc    = (int*)(ws + OFF_QC);
        int*      queue = (int*)(ws + OFF_QUEUE);
        float4*   part  = (float4*)(ws + OFF_PART);
        ushort_t* s1p   = (ushort_t*)(ws + OFF_S1P);
        ushort_t* s2p   = (ushort_t*)(ws + OFF_S2P);
        hipMemsetAsync(ws + OFF_QC, 0, 16, stream);
        k_convert<<<dim3(1024), dim3(256), 0, stream>>>(s1, s2, s1p, s2p);
        k_score<<<dim3(2048), dim3(256), 0, stream>>>(s1p, s2p, part);
        k_epilogue<<<dim3(2048), dim3(256), 0, stream>>>(s2, part, u, oh, qc, queue);
        k_fixup<<<dim3(128), dim3(256), 0, stream>>>(s1, s2, u, oh, qc, queue, 16384);
    } else {
        int  qcap   = 0;
        int* qcount = nullptr;
        int* queue  = nullptr;
        if (ws_size >= 256) {
            qcount = (int*)d_ws;
            queue  = (int*)d_ws + 4;
            size_t cap = (ws_size - 16) / sizeof(int);
            qcap = (int)(cap > (size_t)(BB * T1) ? (size_t)(BB * T1) : cap);
            hipMemsetAsync(d_ws, 0, 16, stream);
        }
        k_score_fb<<<dim3(BB * (T1 / 64)), dim3(512), 0, stream>>>(
            s1, s2, u, oh, qcount, queue, qcap);
        if (qcap > 0)
            k_fixup<<<dim3(64), dim3(256), 0, stream>>>(
                s1, s2, u, oh, qcount, queue, qcap);
    }
}

// Round 7
// 299.302 us; speedup vs baseline: 2.2769x; 1.0187x over previous
//
#include <hip/hip_runtime.h>
#include <math.h>

typedef unsigned short ushort_t;

constexpr int BB = 8, T1 = 2048, T2 = 2048, D = 256;
constexpr float MARGIN = 4e-3f;   // 3-limb bf16 score error ~1e-4; 40x headroom

// ---- workspace layout (fast path) ----
constexpr size_t OFF_QC    = 0;                         // int counter (16 B)
constexpr size_t OFF_QUEUE = 64;                        // 16384 ints
constexpr size_t OFF_S1P   = (size_t)2 << 20;           // packed bf16 hi/lo s1 (16.8 MB)
constexpr size_t SZ_PACK   = (size_t)BB * 128 * 8 * 2 * 64 * 16; // b*tile16*g*limb*lane*16B
constexpr size_t OFF_S2P   = OFF_S1P + SZ_PACK;
constexpr size_t WS_NEEDED = OFF_S2P + SZ_PACK;         // ~35.7 MB

typedef __attribute__((ext_vector_type(8))) __bf16 bf16x8;
typedef __attribute__((ext_vector_type(4))) float  f32x4;

__device__ __forceinline__ unsigned f2bf(float x) {
    unsigned u = __float_as_uint(x);
    return (u + 0x7fffu + ((u >> 16) & 1u)) >> 16;
}
__device__ __forceinline__ float bf2f(unsigned h) { return __uint_as_float(h << 16); }

// ============================================================================
// K0: convert fp32 -> bf16 hi/lo, packed in MFMA-fragment tile order.
// Tile = 16 rows x 32 k. Chunk (1 KB) = [lane 0..63][8 shorts],
// lane = (row&15) + 16*((k&31)>>3), element i -> k = (lane>>4)*8 + i.
// Flat: [b][tile16 (128)][g (8)][limb (2)][lane (64)][16 B].  (r4-verified)
// ============================================================================
__global__ __launch_bounds__(256) void k_convert(
    const float* __restrict__ s1, const float* __restrict__ s2,
    ushort_t* __restrict__ s1p, ushort_t* __restrict__ s2p)
{
    __shared__ __align__(16) ushort_t L[16384];   // 32 KB staging (2 tile16 of output)
    const int bx = blockIdx.x;
    const int tensor = bx >> 9, b = (bx >> 6) & 7, rt = bx & 63;  // rt: 32-row group
    const float* src = (tensor ? s2 : s1) + ((size_t)b * 2048 + rt * 32) * 256;
    ushort_t* dst = (tensor ? s2p : s1p) + (size_t)(b * 128 + rt * 2) * 8192;
    const int t = threadIdx.x;
#pragma unroll
    for (int i = 0; i < 8; ++i) {
        int f = i * 256 + t, rw = f >> 6, c4 = f & 63, k0 = c4 * 4;
        float4 v = *(const float4*)(src + rw * 256 + k0);
        unsigned hx = f2bf(v.x), hy = f2bf(v.y), hz = f2bf(v.z), hw = f2bf(v.w);
        ushort4 hi = make_ushort4((ushort_t)hx, (ushort_t)hy, (ushort_t)hz, (ushort_t)hw);
        ushort4 lo = make_ushort4((ushort_t)f2bf(v.x - bf2f(hx)), (ushort_t)f2bf(v.y - bf2f(hy)),
                                  (ushort_t)f2bf(v.z - bf2f(hz)), (ushort_t)f2bf(v.w - bf2f(hw)));
        int tile = rw >> 4, m = rw & 15, g = k0 >> 5;
        int lane = m + 16 * ((k0 >> 3) & 3), i0 = k0 & 7;
        int off = (tile * 8 + g) * 1024 + lane * 8 + i0;   // limb stride 512 shorts
        *(ushort4*)(&L[off])       = hi;
        *(ushort4*)(&L[off + 512]) = lo;
    }
    __syncthreads();
#pragma unroll
    for (int i = 0; i < 8; ++i) {
        int cidx = i * 256 + t;                             // 2048 x 16 B = 32 KB
        ((uint4*)dst)[cidx] = ((const uint4*)L)[cidx];
    }
}

// ============================================================================
// K1 (r7): fused A-resident stream-B score + argmax + one-hot/gather epilogue.
// Grid 256 (1 block/CU): b=bx&7 (batch -> XCD-local s2p slice, 2.1 MB in L2),
// rg=bx>>3 (64-row group). A strip (4 tile16, 64 KB, fragment order) staged
// to LDS ONCE; each of 4 waves owns a contiguous 512-j stream and reads B
// fragments straight from global/L2 (each B fragment read once per block:
// 528 MB total vs r6's 1 GB). B double-buffered one g ahead. One-hot zeros
// streamed during the K-loop (overlaps MFMA); final pass writes the 1.0s + u.
// ============================================================================
__global__ __launch_bounds__(256, 1) void k_score_fused(
    const ushort_t* __restrict__ s1p, const ushort_t* __restrict__ s2p,
    const float* __restrict__ s2,
    float* __restrict__ u, float* __restrict__ oh,
    int* __restrict__ qcount, int* __restrict__ queue)
{
    __shared__ __align__(16) ushort_t AL[4 * 8192];   // 64 KB: 4 tile16 x (8g x 2limb x 1KB)
    __shared__ float4 mrg[64][4];
    __shared__ int    idxs[64];

    const int bx = blockIdx.x;
    const int b = bx & 7, rg = bx >> 3;               // 32 row-groups of 64
    const int r0 = rg * 64;
    const int t = threadIdx.x, w = t >> 6, l = t & 63;
    const int q = l >> 4, n = l & 15;

    // ---- stage A strip once (layout-preserving copy) ----
    {
        const uint4* src = (const uint4*)(s1p + (size_t)(b * 128 + rg * 4) * 8192);
        uint4* dst = (uint4*)AL;
#pragma unroll
        for (int i = 0; i < 16; ++i) dst[i * 256 + t] = src[i * 256 + t];
    }
    __syncthreads();

    // running top-2 per (rt, reg)  [row = rt*16 + q*4 + reg, col-subset = n + 16*jj...]
    float v1[4][4], v2[4][4]; int i1r[4][4];
#pragma unroll
    for (int rt = 0; rt < 4; ++rt)
#pragma unroll
        for (int r = 0; r < 4; ++r) { v1[rt][r] = -INFINITY; v2[rt][r] = -INFINITY; i1r[rt][r] = 0; }

    float* ohb = oh + ((size_t)b * T1 + r0) * T2;
    const float4 z4 = make_float4(0.f, 0.f, 0.f, 0.f);

#pragma unroll 1
    for (int jtb = 0; jtb < 8; ++jtb) {               // 8 x 4 tile16 = wave's 512 j
        f32x4 acc[4][4];                               // [jj][rt]
#pragma unroll
        for (int jj = 0; jj < 4; ++jj)
#pragma unroll
            for (int rt = 0; rt < 4; ++rt)
#pragma unroll
                for (int r = 0; r < 4; ++r) acc[jj][rt][r] = 0.f;

        const ushort_t* Bb = s2p + (size_t)(b * 128 + w * 32 + jtb * 4) * 8192 + l * 8;

        bf16x8 bF0[4][2], bF1[4][2];
#pragma unroll
        for (int jj = 0; jj < 4; ++jj) {               // g=0 fragments
            bF0[jj][0] = *(const bf16x8*)(Bb + (size_t)jj * 8192);
            bF0[jj][1] = *(const bf16x8*)(Bb + (size_t)jj * 8192 + 512);
        }

        auto g_body = [&](int g, bf16x8 (&bCur)[4][2], bf16x8 (&bNext)[4][2], bool pref) {
            if (pref) {
                const ushort_t* Bn = Bb + (g + 1) * 1024;
#pragma unroll
                for (int jj = 0; jj < 4; ++jj) {
                    bNext[jj][0] = *(const bf16x8*)(Bn + (size_t)jj * 8192);
                    bNext[jj][1] = *(const bf16x8*)(Bn + (size_t)jj * 8192 + 512);
                }
            }
            bf16x8 aF[4][2];
#pragma unroll
            for (int rt = 0; rt < 4; ++rt) {
                aF[rt][0] = *(const bf16x8*)(&AL[(rt * 8 + g) * 1024 + l * 8]);
                aF[rt][1] = *(const bf16x8*)(&AL[(rt * 8 + g) * 1024 + 512 + l * 8]);
            }
#pragma unroll
            for (int jj = 0; jj < 4; ++jj)
#pragma unroll
                for (int rt = 0; rt < 4; ++rt) {
                    acc[jj][rt] = __builtin_amdgcn_mfma_f32_16x16x32_bf16(aF[rt][0], bCur[jj][0], acc[jj][rt], 0, 0, 0);
                    acc[jj][rt] = __builtin_amdgcn_mfma_f32_16x16x32_bf16(aF[rt][0], bCur[jj][1], acc[jj][rt], 0, 0, 0);
                    acc[jj][rt] = __builtin_amdgcn_mfma_f32_16x16x32_bf16(aF[rt][1], bCur[jj][0], acc[jj][rt], 0, 0, 0);
                }
        };

#pragma unroll 1
        for (int g2 = 0; g2 < 4; ++g2) {
            g_body(2 * g2,     bF0, bF1, true);
            g_body(2 * g2 + 1, bF1, bF0, g2 < 3);
        }

        // fold this jtb's 64 j into running top-2 (j ascending across jtb, jj)
#pragma unroll
        for (int rt = 0; rt < 4; ++rt)
#pragma unroll
            for (int reg = 0; reg < 4; ++reg)
#pragma unroll
                for (int jj = 0; jj < 4; ++jj) {
                    float v = acc[jj][rt][reg];
                    int j = w * 512 + jtb * 64 + jj * 16 + n;
                    if (v > v1[rt][reg])      { v2[rt][reg] = v1[rt][reg]; v1[rt][reg] = v; i1r[rt][reg] = j; }
                    else if (v > v2[rt][reg]) { v2[rt][reg] = v; }
                }

        // progressive one-hot zero-fill for this wave's j-slice (overlaps MFMA of
        // other waves; the single 1.0 is written after the barrier below)
        {
            int jbase = w * 512 + jtb * 64;
#pragma unroll
            for (int i = 0; i < 16; ++i) {
                int row = i * 4 + (l >> 4);
                int c4  = l & 15;
                *(float4*)(ohb + (size_t)row * T2 + jbase + c4 * 4) = z4;
            }
        }
    }

    // reduce across the 16 column-lanes, publish per-wave (per-512-j) partials
#pragma unroll
    for (int rt = 0; rt < 4; ++rt)
#pragma unroll
        for (int reg = 0; reg < 4; ++reg) {
            float a1 = v1[rt][reg], a2 = v2[rt][reg]; int ai = i1r[rt][reg];
#pragma unroll
            for (int off = 1; off < 16; off <<= 1) {
                float b1 = __shfl_xor(a1, off);
                int   bi = __shfl_xor(ai, off);
                float b2 = __shfl_xor(a2, off);
                if (b1 > a1 || (b1 == a1 && bi < ai)) { a2 = fmaxf(a1, b2); a1 = b1; ai = bi; }
                else                                   { a2 = fmaxf(b1, a2); }
            }
            if (n == rt * 4 + reg)   // 4 lanes (q=0..3) active, distinct rows
                mrg[rt * 16 + q * 4 + reg][w] = make_float4(a1, a2, __int_as_float(ai), 0.f);
        }
    __syncthreads();

    if (t < 64) {                     // merge 4 wave partials (w ascending = j ascending)
        float4 p = mrg[t][0];
        float V1 = p.x, V2 = p.y; int I = __float_as_int(p.z);
#pragma unroll
        for (int h = 1; h < 4; ++h) {
            float4 c = mrg[t][h];
            int ci = __float_as_int(c.z);
            if (c.x > V1 || (c.x == V1 && ci < I)) { V2 = fmaxf(V1, c.y); V1 = c.x; I = ci; }
            else                                    { V2 = fmaxf(V2, c.x); }
        }
        idxs[t] = I;
        if ((V1 - V2) < MARGIN) {
            int pos = atomicAdd(qcount, 1);
            if (pos < 16384) queue[pos] = b * T1 + r0 + t;
        }
        ohb[(size_t)t * T2 + I] = 1.0f;   // zeros for this row drained at barrier
    }
    __syncthreads();

    // u gather: 64 rows x 64 float4, coalesced
    const float* s2b = s2 + (size_t)b * T2 * D;
    float* ub = u + ((size_t)b * T1 + r0) * D;
#pragma unroll
    for (int i = 0; i < 16; ++i) {
        int flat = i * 256 + t, row = flat >> 6, c4 = flat & 63;
        float4 v = *(const float4*)(s2b + (size_t)idxs[row] * D + c4 * 4);
        *(float4*)(ub + (size_t)row * D + c4 * 4) = v;
    }
}

// ============================================================================
// K3: exact float64 recompute for flagged (near-tie) rows.
// ============================================================================
__global__ __launch_bounds__(256) void k_fixup(
    const float* __restrict__ s1, const float* __restrict__ s2,
    float* __restrict__ u, float* __restrict__ oh,
    const int* __restrict__ qcount, const int* __restrict__ queue, int qcap)
{
    __shared__ double s1d[D];
    __shared__ double rv[256];
    __shared__ int    rj[256];
    int nq = *qcount;
    if (nq > qcap) nq = qcap;
    const int t = threadIdx.x;
    for (int qi = blockIdx.x; qi < nq; qi += gridDim.x) {
        int rg = queue[qi];
        int b = rg >> 11, i = rg & (T1 - 1);
        __syncthreads();
        s1d[t] = (double)s1[((size_t)b * T1 + i) * D + t];
        __syncthreads();
        double bv = -INFINITY; int bj = 0;
        for (int jj = 0; jj < T2 / 256; ++jj) {
            int j = t + jj * 256;
            const float* row = s2 + ((size_t)b * T2 + j) * D;
            double s = 0.0;
            for (int k = 0; k < D; ++k) s = fma((double)row[k], s1d[k], s);
            if (s > bv) { bv = s; bj = j; }
        }
        rv[t] = bv; rj[t] = bj;
        __syncthreads();
        for (int stride = 128; stride > 0; stride >>= 1) {
            if (t < stride) {
                double ov = rv[t + stride]; int oj = rj[t + stride];
                if (ov > rv[t] || (ov == rv[t] && oj < rj[t])) { rv[t] = ov; rj[t] = oj; }
            }
            __syncthreads();
        }
        int best = rj[0];
        float* ohrow = oh + ((size_t)b * T1 + i) * T2;
#pragma unroll
        for (int jj = 0; jj < T2 / 256; ++jj) {
            int j = t + jj * 256;
            ohrow[j] = (j == best) ? 1.f : 0.f;
        }
        u[((size_t)b * T1 + i) * D + t] = s2[((size_t)b * T2 + best) * D + t];
    }
}

// ============================================================================
// Fallback (ws too small): round-2 fused kernel, verified correct.
// ============================================================================
constexpr int FB_AST = 264, FB_BST = 72;

__global__ __launch_bounds__(512, 2) void k_score_fb(
    const float* __restrict__ s1, const float* __restrict__ s2,
    float* __restrict__ u, float* __restrict__ oh,
    int* __restrict__ qcount, int* __restrict__ queue, int qcap)
{
    __shared__ __align__(16) short Ah[64 * FB_AST];
    __shared__ __align__(16) short Al[64 * FB_AST];
    __shared__ __align__(16) short Bh[256 * FB_BST];
    __shared__ __align__(16) short Bl[256 * FB_BST];
    __shared__ float cv1[64][4], cv2[64][4];
    __shared__ int   ci1[64][4], idx_s[64];

    const int bx = blockIdx.x;
    const int b  = bx & 7;
    const int r0 = (bx >> 3) * 64;
    const float* s1b = s1 + ((size_t)b * T1 + r0) * D;
    const float* s2b = s2 + (size_t)b * T2 * D;

    const int t = threadIdx.x;
    const int w = t >> 6, l = t & 63, q = l >> 4, ln = l & 15;
    const int rh = w >> 2;
    const int jq = w & 3;

    float4 pa[8];
#pragma unroll
    for (int i = 0; i < 8; ++i) {
        int flat = i * 512 + t, row = flat >> 6, f4 = flat & 63;
        pa[i] = *(const float4*)(s1b + row * D + f4 * 4);
    }
    float4 pb[8];
#pragma unroll
    for (int i = 0; i < 8; ++i) {
        int flat = i * 512 + t, jrow = flat >> 4, f4 = flat & 15;
        pb[i] = *(const float4*)(s2b + (size_t)jrow * D + f4 * 4);
    }
#pragma unroll
    for (int i = 0; i < 8; ++i) {
        int flat = i * 512 + t, row = flat >> 6, f4 = flat & 63;
        float4 v = pa[i];
        unsigned hx = f2bf(v.x), hy = f2bf(v.y), hz = f2bf(v.z), hw = f2bf(v.w);
        uint2 hh, ll;
        hh.x = hx | (hy << 16); hh.y = hz | (hw << 16);
        ll.x = f2bf(v.x - bf2f(hx)) | (f2bf(v.y - bf2f(hy)) << 16);
        ll.y = f2bf(v.z - bf2f(hz)) | (f2bf(v.w - bf2f(hw)) << 16);
        *(uint2*)(&Ah[row * FB_AST + f4 * 4]) = hh;
        *(uint2*)(&Al[row * FB_AST + f4 * 4]) = ll;
    }

    float v1[2][4], v2[2][4]; int i1[2][4];
#pragma unroll
    for (int rt = 0; rt < 2; ++rt)
#pragma unroll
        for (int r = 0; r < 4; ++r) { v1[rt][r] = -INFINITY; v2[rt][r] = -INFINITY; i1[rt][r] = 0; }

    f32x4 acc[2][4];

    for (int c = 0; c < 32; ++c) {
        const int iter = c >> 2, kc = c & 3;
        if (kc == 0) {
#pragma unroll
            for (int rt = 0; rt < 2; ++rt)
#pragma unroll
                for (int jt = 0; jt < 4; ++jt)
#pragma unroll
                    for (int r = 0; r < 4; ++r) acc[rt][jt][r] = 0.f;
        }
        __syncthreads();
#pragma unroll
        for (int i = 0; i < 8; ++i) {
            int flat = i * 512 + t, jrow = flat >> 4, f4 = flat & 15;
            float4 v = pb[i];
            unsigned hx = f2bf(v.x), hy = f2bf(v.y), hz = f2bf(v.z), hw = f2bf(v.w);
            uint2 hh, ll;
            hh.x = hx | (hy << 16); hh.y = hz | (hw << 16);
            ll.x = f2bf(v.x - bf2f(hx)) | (f2bf(v.y - bf2f(hy)) << 16);
            ll.y = f2bf(v.z - bf2f(hz)) | (f2bf(v.w - bf2f(hw)) << 16);
            *(uint2*)(&Bh[jrow * FB_BST + f4 * 4]) = hh;
            *(uint2*)(&Bl[jrow * FB_BST + f4 * 4]) = ll;
        }
        if (c < 31) {
            int c2 = c + 1, it2 = c2 >> 2, kc2 = c2 & 3;
#pragma unroll
            for (int i = 0; i < 8; ++i) {
                int flat = i * 512 + t, jrow = flat >> 4, f4 = flat & 15;
                pb[i] = *(const float4*)(s2b + (size_t)(it2 * 256 + jrow) * D + kc2 * 64 + f4 * 4);
            }
        }
        __syncthreads();

#pragma unroll
        for (int ks = 0; ks < 2; ++ks) {
            const int kA = kc * 64 + ks * 32 + q * 8;
            bf16x8 ah[2], al8[2];
#pragma unroll
            for (int rt = 0; rt < 2; ++rt) {
                int off = (rh * 32 + rt * 16 + ln) * FB_AST + kA;
                ah[rt]  = *(const bf16x8*)(&Ah[off]);
                al8[rt] = *(const bf16x8*)(&Al[off]);
            }
#pragma unroll
            for (int jt = 0; jt < 4; ++jt) {
                int boff = (jq * 64 + jt * 16 + ln) * FB_BST + ks * 32 + q * 8;
                bf16x8 bh = *(const bf16x8*)(&Bh[boff]);
                bf16x8 bl = *(const bf16x8*)(&Bl[boff]);
#pragma unroll
                for (int rt = 0; rt < 2; ++rt) {
                    acc[rt][jt] = __builtin_amdgcn_mfma_f32_16x16x32_bf16(ah[rt],  bh, acc[rt][jt], 0, 0, 0);
                    acc[rt][jt] = __builtin_amdgcn_mfma_f32_16x16x32_bf16(ah[rt],  bl, acc[rt][jt], 0, 0, 0);
                    acc[rt][jt] = __builtin_amdgcn_mfma_f32_16x16x32_bf16(al8[rt], bh, acc[rt][jt], 0, 0, 0);
                }
            }
        }

        if (kc == 3) {
#pragma unroll
            for (int rt = 0; rt < 2; ++rt)
#pragma unroll
                for (int jt = 0; jt < 4; ++jt)
#pragma unroll
                    for (int r = 0; r < 4; ++r) {
                        float val = acc[rt][jt][r];
                        int j = iter * 256 + jq * 64 + jt * 16 + ln;
                        if (val > v1[rt][r]) { v2[rt][r] = v1[rt][r]; v1[rt][r] = val; i1[rt][r] = j; }
                        else if (val > v2[rt][r]) v2[rt][r] = val;
                    }
        }
    }

#pragma unroll
    for (int rt = 0; rt < 2; ++rt)
#pragma unroll
        for (int r = 0; r < 4; ++r) {
            float a1 = v1[rt][r], a2 = v2[rt][r]; int ai = i1[rt][r];
#pragma unroll
            for (int off = 1; off < 16; off <<= 1) {
                float b1 = __shfl_xor(a1, off);
                int   bi = __shfl_xor(ai, off);
                float b2 = __shfl_xor(a2, off);
                if (b1 > a1 || (b1 == a1 && bi < ai)) { a2 = fmaxf(a1, b2); a1 = b1; ai = bi; }
                else                                   { a2 = fmaxf(b1, a2); }
            }
            if (ln == 0) {
                int row = rh * 32 + rt * 16 + q * 4 + r;
                cv1[row][jq] = a1; cv2[row][jq] = a2; ci1[row][jq] = ai;
            }
        }
    __syncthreads();

    if (t < 64) {
        float V1 = cv1[t][0], V2 = cv2[t][0]; int I = ci1[t][0];
#pragma unroll
        for (int h = 1; h < 4; ++h) {
            float c1 = cv1[t][h], c2 = cv2[t][h]; int ci = ci1[t][h];
            if (c1 > V1 || (c1 == V1 && ci < I)) { V2 = fmaxf(V1, c2); V1 = c1; I = ci; }
            else                                  { V2 = fmaxf(V2, c1); }
        }
        idx_s[t] = I;
        if (qcap > 0 && (V1 - V2) < MARGIN) {
            int pos = atomicAdd(qcount, 1);
            if (pos < qcap) queue[pos] = b * T1 + r0 + t;
        }
    }
    __syncthreads();

    float* ub = u + ((size_t)b * T1 + r0) * D;
#pragma unroll
    for (int i = 0; i < 8; ++i) {
        int flat = i * 512 + t, row = flat >> 6, f4 = flat & 63;
        float4 v = *(const float4*)(s2b + (size_t)idx_s[row] * D + f4 * 4);
        *(float4*)(ub + (size_t)row * D + f4 * 4) = v;
    }
    float* ohb = oh + ((size_t)b * T1 + r0) * T2;
#pragma unroll 4
    for (int i = 0; i < 64; ++i) {
        int flat = i * 512 + t, row = flat >> 9, f4 = flat & 511;
        int base = f4 * 4, id = idx_s[row];
        float4 vv;
        vv.x = (base     == id) ? 1.f : 0.f;
        vv.y = (base + 1 == id) ? 1.f : 0.f;
        vv.z = (base + 2 == id) ? 1.f : 0.f;
        vv.w = (base + 3 == id) ? 1.f : 0.f;
        *(float4*)(ohb + (size_t)row * T2 + base) = vv;
    }
}

extern "C" void kernel_launch(void* const* d_in, const int* in_sizes, int n_in,
                              void* d_out, int out_size, void* d_ws, size_t ws_size,
                              hipStream_t stream)
{
    const float* s1 = (const float*)d_in[0];
    const float* s2 = (const float*)d_in[1];
    float* u  = (float*)d_out;                       // [8,2048,256]
    float* oh = u + (size_t)BB * T1 * D;             // [8,2048,2048]
    char* ws = (char*)d_ws;

    if (ws_size >= WS_NEEDED) {
        int*      qc    = (int*)(ws + OFF_QC);
        int*      queue = (int*)(ws + OFF_QUEUE);
        ushort_t* s1p   = (ushort_t*)(ws + OFF_S1P);
        ushort_t* s2p   = (ushort_t*)(ws + OFF_S2P);
        hipMemsetAsync(ws + OFF_QC, 0, 16, stream);
        k_convert<<<dim3(1024), dim3(256), 0, stream>>>(s1, s2, s1p, s2p);
        k_score_fused<<<dim3(256), dim3(256), 0, stream>>>(s1p, s2p, s2, u, oh, qc, queue);
        k_fixup<<<dim3(128), dim3(256), 0, stream>>>(s1, s2, u, oh, qc, queue, 16384);
    } else {
        int  qcap   = 0;
        int* qcount = nullptr;
        int* queue  = nullptr;
        if (ws_size >= 256) {
            qcount = (int*)d_ws;
            queue  = (int*)d_ws + 4;
            size_t cap = (ws_size - 16) / sizeof(int);
            qcap = (int)(cap > (size_t)(BB * T1) ? (size_t)(BB * T1) : cap);
            hipMemsetAsync(d_ws, 0, 16, stream);
        }
        k_score_fb<<<dim3(BB * (T1 / 64)), dim3(512), 0, stream>>>(
            s1, s2, u, oh, qcount, queue, qcap);
        if (qcap > 0)
            k_fixup<<<dim3(64), dim3(256), 0, stream>>>(
                s1, s2, u, oh, qcount, queue, qcap);
    }
}

// Round 8
// 273.427 us; speedup vs baseline: 2.4923x; 1.0946x over previous
//
#include <hip/hip_runtime.h>
#include <math.h>

typedef unsigned short ushort_t;

constexpr int BB = 8, T1 = 2048, T2 = 2048, D = 256;
constexpr float MARGIN = 4e-3f;   // 3-limb bf16 score error ~1e-4; 40x headroom

// ---- workspace layout (fast path) ----
constexpr size_t OFF_QC    = 0;                         // int counter (16 B)
constexpr size_t OFF_QUEUE = 64;                        // 16384 ints
constexpr size_t OFF_S1P   = (size_t)2 << 20;           // packed bf16 hi/lo s1 (16.8 MB)
constexpr size_t SZ_PACK   = (size_t)BB * 128 * 8 * 2 * 64 * 16; // b*tile16*g*limb*lane*16B
constexpr size_t OFF_S2P   = OFF_S1P + SZ_PACK;
constexpr size_t WS_NEEDED = OFF_S2P + SZ_PACK;         // ~35.7 MB

typedef __attribute__((ext_vector_type(8))) __bf16 bf16x8;
typedef __attribute__((ext_vector_type(4))) float  f32x4;

__device__ __forceinline__ unsigned f2bf(float x) {
    unsigned u = __float_as_uint(x);
    return (u + 0x7fffu + ((u >> 16) & 1u)) >> 16;
}
__device__ __forceinline__ float bf2f(unsigned h) { return __uint_as_float(h << 16); }

// ============================================================================
// K0: convert fp32 -> bf16 hi/lo, packed in MFMA-fragment tile order.
// Tile = 16 rows x 32 k. Chunk (1 KB) = [lane 0..63][8 shorts],
// lane = (row&15) + 16*((k&31)>>3), element i -> k = (lane>>4)*8 + i.
// Flat: [b][tile16 (128)][g (8)][limb (2)][lane (64)][16 B].  (r4-verified)
// ============================================================================
__global__ __launch_bounds__(256) void k_convert(
    const float* __restrict__ s1, const float* __restrict__ s2,
    ushort_t* __restrict__ s1p, ushort_t* __restrict__ s2p)
{
    __shared__ __align__(16) ushort_t L[16384];   // 32 KB staging (2 tile16 of output)
    const int bx = blockIdx.x;
    const int tensor = bx >> 9, b = (bx >> 6) & 7, rt = bx & 63;  // rt: 32-row group
    const float* src = (tensor ? s2 : s1) + ((size_t)b * 2048 + rt * 32) * 256;
    ushort_t* dst = (tensor ? s2p : s1p) + (size_t)(b * 128 + rt * 2) * 8192;
    const int t = threadIdx.x;
#pragma unroll
    for (int i = 0; i < 8; ++i) {
        int f = i * 256 + t, rw = f >> 6, c4 = f & 63, k0 = c4 * 4;
        float4 v = *(const float4*)(src + rw * 256 + k0);
        unsigned hx = f2bf(v.x), hy = f2bf(v.y), hz = f2bf(v.z), hw = f2bf(v.w);
        ushort4 hi = make_ushort4((ushort_t)hx, (ushort_t)hy, (ushort_t)hz, (ushort_t)hw);
        ushort4 lo = make_ushort4((ushort_t)f2bf(v.x - bf2f(hx)), (ushort_t)f2bf(v.y - bf2f(hy)),
                                  (ushort_t)f2bf(v.z - bf2f(hz)), (ushort_t)f2bf(v.w - bf2f(hw)));
        int tile = rw >> 4, m = rw & 15, g = k0 >> 5;
        int lane = m + 16 * ((k0 >> 3) & 3), i0 = k0 & 7;
        int off = (tile * 8 + g) * 1024 + lane * 8 + i0;   // limb stride 512 shorts
        *(ushort4*)(&L[off])       = hi;
        *(ushort4*)(&L[off + 512]) = lo;
    }
    __syncthreads();
#pragma unroll
    for (int i = 0; i < 8; ++i) {
        int cidx = i * 256 + t;                             // 2048 x 16 B = 32 KB
        ((uint4*)dst)[cidx] = ((const uint4*)L)[cidx];
    }
}

// ============================================================================
// K1 (r8): fused A-resident stream-B score, 512-thread blocks (2 waves/SIMD).
// r7 post-mortem: grid 256 x 4 waves = 1 wave/SIMD -> every vmcnt/lgkmcnt/
// store stall fully exposed (MfmaUtil 21%, dur 92.8). r8: 8 waves/block,
// each wave owns a 256-j stream; B prefetch chains across jtb boundaries
// (last g of jtb prefetches next jtb's g0) so the load pipe never drains.
// Traffic unchanged: A once to LDS, each B fragment read once per block.
// ============================================================================
__global__ __launch_bounds__(512, 2) void k_score_fused(
    const ushort_t* __restrict__ s1p, const ushort_t* __restrict__ s2p,
    const float* __restrict__ s2,
    float* __restrict__ u, float* __restrict__ oh,
    int* __restrict__ qcount, int* __restrict__ queue)
{
    __shared__ __align__(16) ushort_t AL[4 * 8192];   // 64 KB: 4 tile16 x (8g x 2limb x 1KB)
    __shared__ float4 mrg[64][8];
    __shared__ int    idxs[64];

    const int bx = blockIdx.x;
    const int b = bx & 7, rg = bx >> 3;               // 32 row-groups of 64
    const int r0 = rg * 64;
    const int t = threadIdx.x, w = t >> 6, l = t & 63;
    const int q = l >> 4, n = l & 15;

    // ---- stage A strip once (layout-preserving copy) ----
    {
        const uint4* src = (const uint4*)(s1p + (size_t)(b * 128 + rg * 4) * 8192);
        uint4* dst = (uint4*)AL;
#pragma unroll
        for (int i = 0; i < 8; ++i) dst[i * 512 + t] = src[i * 512 + t];
    }
    mrg[t >> 3][t & 7] = make_float4(-INFINITY, -INFINITY, __int_as_float(0), 0.f);
    __syncthreads();

    // running top-2 per (rt, reg)  [row = rt*16 + q*4 + reg]
    float v1[4][4], v2[4][4]; int i1r[4][4];
#pragma unroll
    for (int rt = 0; rt < 4; ++rt)
#pragma unroll
        for (int r = 0; r < 4; ++r) { v1[rt][r] = -INFINITY; v2[rt][r] = -INFINITY; i1r[rt][r] = 0; }

    float* ohb = oh + ((size_t)b * T1 + r0) * T2;
    const float4 z4 = make_float4(0.f, 0.f, 0.f, 0.f);

    // wave's 16 tile16 (256 j), per-lane fragment base
    const ushort_t* Bw = s2p + (size_t)(b * 128 + w * 16) * 8192 + l * 8;

    f32x4 acc[4][4];                                   // [jj][rt]
    bf16x8 bF0[4][2], bF1[4][2];
#pragma unroll
    for (int jj = 0; jj < 4; ++jj) {                   // jtb=0, g=0 fragments
        bF0[jj][0] = *(const bf16x8*)(Bw + (size_t)jj * 8192);
        bF0[jj][1] = *(const bf16x8*)(Bw + (size_t)jj * 8192 + 512);
    }

#pragma unroll 1
    for (int jtb = 0; jtb < 4; ++jtb) {                // 4 x 4 tile16 = wave's 256 j
#pragma unroll
        for (int jj = 0; jj < 4; ++jj)
#pragma unroll
            for (int rt = 0; rt < 4; ++rt)
#pragma unroll
                for (int r = 0; r < 4; ++r) acc[jj][rt][r] = 0.f;

        const ushort_t* Bb = Bw + (size_t)jtb * 4 * 8192;

        auto g_body = [&](int g, const ushort_t* prefPtr,
                          bf16x8 (&bCur)[4][2], bf16x8 (&bNext)[4][2]) {
            if (prefPtr) {
#pragma unroll
                for (int jj = 0; jj < 4; ++jj) {
                    bNext[jj][0] = *(const bf16x8*)(prefPtr + (size_t)jj * 8192);
                    bNext[jj][1] = *(const bf16x8*)(prefPtr + (size_t)jj * 8192 + 512);
                }
            }
            bf16x8 aF[4][2];
#pragma unroll
            for (int rt = 0; rt < 4; ++rt) {
                aF[rt][0] = *(const bf16x8*)(&AL[(rt * 8 + g) * 1024 + l * 8]);
                aF[rt][1] = *(const bf16x8*)(&AL[(rt * 8 + g) * 1024 + 512 + l * 8]);
            }
#pragma unroll
            for (int jj = 0; jj < 4; ++jj)
#pragma unroll
                for (int rt = 0; rt < 4; ++rt) {
                    acc[jj][rt] = __builtin_amdgcn_mfma_f32_16x16x32_bf16(aF[rt][0], bCur[jj][0], acc[jj][rt], 0, 0, 0);
                    acc[jj][rt] = __builtin_amdgcn_mfma_f32_16x16x32_bf16(aF[rt][0], bCur[jj][1], acc[jj][rt], 0, 0, 0);
                    acc[jj][rt] = __builtin_amdgcn_mfma_f32_16x16x32_bf16(aF[rt][1], bCur[jj][0], acc[jj][rt], 0, 0, 0);
                }
        };

#pragma unroll 1
        for (int g2 = 0; g2 < 4; ++g2) {
            const int g0 = 2 * g2;
            g_body(g0, Bb + (g0 + 1) * 1024, bF0, bF1);
            const ushort_t* nxt =
                (g2 < 3)   ? Bb + (g0 + 2) * 1024 :
                (jtb < 3)  ? Bb + (size_t)4 * 8192 :      // next jtb, g=0
                             (const ushort_t*)nullptr;
            g_body(g0 + 1, nxt, bF1, bF0);
        }

        // fold this jtb's 64 j into running top-2 (j ascending across jtb, jj)
#pragma unroll
        for (int rt = 0; rt < 4; ++rt)
#pragma unroll
            for (int reg = 0; reg < 4; ++reg)
#pragma unroll
                for (int jj = 0; jj < 4; ++jj) {
                    float v = acc[jj][rt][reg];
                    int j = w * 256 + jtb * 64 + jj * 16 + n;
                    if (v > v1[rt][reg])      { v2[rt][reg] = v1[rt][reg]; v1[rt][reg] = v; i1r[rt][reg] = j; }
                    else if (v > v2[rt][reg]) { v2[rt][reg] = v; }
                }

        // progressive one-hot zero-fill for this wave's j-slice (overlaps other
        // waves' MFMA; the single 1.0 is written after the barrier below)
        {
            int jbase = w * 256 + jtb * 64;
#pragma unroll
            for (int i = 0; i < 16; ++i) {
                int row = i * 4 + (l >> 4);
                int c4  = l & 15;
                *(float4*)(ohb + (size_t)row * T2 + jbase + c4 * 4) = z4;
            }
        }
    }

    // reduce across the 16 column-lanes, publish per-wave (per-256-j) partials
#pragma unroll
    for (int rt = 0; rt < 4; ++rt)
#pragma unroll
        for (int reg = 0; reg < 4; ++reg) {
            float a1 = v1[rt][reg], a2 = v2[rt][reg]; int ai = i1r[rt][reg];
#pragma unroll
            for (int off = 1; off < 16; off <<= 1) {
                float b1 = __shfl_xor(a1, off);
                int   bi = __shfl_xor(ai, off);
                float b2 = __shfl_xor(a2, off);
                if (b1 > a1 || (b1 == a1 && bi < ai)) { a2 = fmaxf(a1, b2); a1 = b1; ai = bi; }
                else                                   { a2 = fmaxf(b1, a2); }
            }
            if (n == rt * 4 + reg)   // 4 lanes (q=0..3) active, distinct rows
                mrg[rt * 16 + q * 4 + reg][w] = make_float4(a1, a2, __int_as_float(ai), 0.f);
        }
    __syncthreads();

    if (t < 64) {                     // merge 8 wave partials (w ascending = j ascending)
        float4 p = mrg[t][0];
        float V1 = p.x, V2 = p.y; int I = __float_as_int(p.z);
#pragma unroll
        for (int h = 1; h < 8; ++h) {
            float4 c = mrg[t][h];
            int ci = __float_as_int(c.z);
            if (c.x > V1 || (c.x == V1 && ci < I)) { V2 = fmaxf(V1, c.y); V1 = c.x; I = ci; }
            else                                    { V2 = fmaxf(V2, c.x); }
        }
        idxs[t] = I;
        if ((V1 - V2) < MARGIN) {
            int pos = atomicAdd(qcount, 1);
            if (pos < 16384) queue[pos] = b * T1 + r0 + t;
        }
        ohb[(size_t)t * T2 + I] = 1.0f;   // zeros for this row drained at barrier
    }
    __syncthreads();

    // u gather: 64 rows x 64 float4, coalesced
    const float* s2b = s2 + (size_t)b * T2 * D;
    float* ub = u + ((size_t)b * T1 + r0) * D;
#pragma unroll
    for (int i = 0; i < 8; ++i) {
        int flat = i * 512 + t, row = flat >> 6, c4 = flat & 63;
        float4 v = *(const float4*)(s2b + (size_t)idxs[row] * D + c4 * 4);
        *(float4*)(ub + (size_t)row * D + c4 * 4) = v;
    }
}

// ============================================================================
// K3: exact float64 recompute for flagged (near-tie) rows.
// ============================================================================
__global__ __launch_bounds__(256) void k_fixup(
    const float* __restrict__ s1, const float* __restrict__ s2,
    float* __restrict__ u, float* __restrict__ oh,
    const int* __restrict__ qcount, const int* __restrict__ queue, int qcap)
{
    __shared__ double s1d[D];
    __shared__ double rv[256];
    __shared__ int    rj[256];
    int nq = *qcount;
    if (nq > qcap) nq = qcap;
    const int t = threadIdx.x;
    for (int qi = blockIdx.x; qi < nq; qi += gridDim.x) {
        int rg = queue[qi];
        int b = rg >> 11, i = rg & (T1 - 1);
        __syncthreads();
        s1d[t] = (double)s1[((size_t)b * T1 + i) * D + t];
        __syncthreads();
        double bv = -INFINITY; int bj = 0;
        for (int jj = 0; jj < T2 / 256; ++jj) {
            int j = t + jj * 256;
            const float* row = s2 + ((size_t)b * T2 + j) * D;
            double s = 0.0;
            for (int k = 0; k < D; ++k) s = fma((double)row[k], s1d[k], s);
            if (s > bv) { bv = s; bj = j; }
        }
        rv[t] = bv; rj[t] = bj;
        __syncthreads();
        for (int stride = 128; stride > 0; stride >>= 1) {
            if (t < stride) {
                double ov = rv[t + stride]; int oj = rj[t + stride];
                if (ov > rv[t] || (ov == rv[t] && oj < rj[t])) { rv[t] = ov; rj[t] = oj; }
            }
            __syncthreads();
        }
        int best = rj[0];
        float* ohrow = oh + ((size_t)b * T1 + i) * T2;
#pragma unroll
        for (int jj = 0; jj < T2 / 256; ++jj) {
            int j = t + jj * 256;
            ohrow[j] = (j == best) ? 1.f : 0.f;
        }
        u[((size_t)b * T1 + i) * D + t] = s2[((size_t)b * T2 + best) * D + t];
    }
}

// ============================================================================
// Fallback (ws too small): round-2 fused kernel, verified correct.
// ============================================================================
constexpr int FB_AST = 264, FB_BST = 72;

__global__ __launch_bounds__(512, 2) void k_score_fb(
    const float* __restrict__ s1, const float* __restrict__ s2,
    float* __restrict__ u, float* __restrict__ oh,
    int* __restrict__ qcount, int* __restrict__ queue, int qcap)
{
    __shared__ __align__(16) short Ah[64 * FB_AST];
    __shared__ __align__(16) short Al[64 * FB_AST];
    __shared__ __align__(16) short Bh[256 * FB_BST];
    __shared__ __align__(16) short Bl[256 * FB_BST];
    __shared__ float cv1[64][4], cv2[64][4];
    __shared__ int   ci1[64][4], idx_s[64];

    const int bx = blockIdx.x;
    const int b  = bx & 7;
    const int r0 = (bx >> 3) * 64;
    const float* s1b = s1 + ((size_t)b * T1 + r0) * D;
    const float* s2b = s2 + (size_t)b * T2 * D;

    const int t = threadIdx.x;
    const int w = t >> 6, l = t & 63, q = l >> 4, ln = l & 15;
    const int rh = w >> 2;
    const int jq = w & 3;

    float4 pa[8];
#pragma unroll
    for (int i = 0; i < 8; ++i) {
        int flat = i * 512 + t, row = flat >> 6, f4 = flat & 63;
        pa[i] = *(const float4*)(s1b + row * D + f4 * 4);
    }
    float4 pb[8];
#pragma unroll
    for (int i = 0; i < 8; ++i) {
        int flat = i * 512 + t, jrow = flat >> 4, f4 = flat & 15;
        pb[i] = *(const float4*)(s2b + (size_t)jrow * D + f4 * 4);
    }
#pragma unroll
    for (int i = 0; i < 8; ++i) {
        int flat = i * 512 + t, row = flat >> 6, f4 = flat & 63;
        float4 v = pa[i];
        unsigned hx = f2bf(v.x), hy = f2bf(v.y), hz = f2bf(v.z), hw = f2bf(v.w);
        uint2 hh, ll;
        hh.x = hx | (hy << 16); hh.y = hz | (hw << 16);
        ll.x = f2bf(v.x - bf2f(hx)) | (f2bf(v.y - bf2f(hy)) << 16);
        ll.y = f2bf(v.z - bf2f(hz)) | (f2bf(v.w - bf2f(hw)) << 16);
        *(uint2*)(&Ah[row * FB_AST + f4 * 4]) = hh;
        *(uint2*)(&Al[row * FB_AST + f4 * 4]) = ll;
    }

    float v1[2][4], v2[2][4]; int i1[2][4];
#pragma unroll
    for (int rt = 0; rt < 2; ++rt)
#pragma unroll
        for (int r = 0; r < 4; ++r) { v1[rt][r] = -INFINITY; v2[rt][r] = -INFINITY; i1[rt][r] = 0; }

    f32x4 acc[2][4];

    for (int c = 0; c < 32; ++c) {
        const int iter = c >> 2, kc = c & 3;
        if (kc == 0) {
#pragma unroll
            for (int rt = 0; rt < 2; ++rt)
#pragma unroll
                for (int jt = 0; jt < 4; ++jt)
#pragma unroll
                    for (int r = 0; r < 4; ++r) acc[rt][jt][r] = 0.f;
        }
        __syncthreads();
#pragma unroll
        for (int i = 0; i < 8; ++i) {
            int flat = i * 512 + t, jrow = flat >> 4, f4 = flat & 15;
            float4 v = pb[i];
            unsigned hx = f2bf(v.x), hy = f2bf(v.y), hz = f2bf(v.z), hw = f2bf(v.w);
            uint2 hh, ll;
            hh.x = hx | (hy << 16); hh.y = hz | (hw << 16);
            ll.x = f2bf(v.x - bf2f(hx)) | (f2bf(v.y - bf2f(hy)) << 16);
            ll.y = f2bf(v.z - bf2f(hz)) | (f2bf(v.w - bf2f(hw)) << 16);
            *(uint2*)(&Bh[jrow * FB_BST + f4 * 4]) = hh;
            *(uint2*)(&Bl[jrow * FB_BST + f4 * 4]) = ll;
        }
        if (c < 31) {
            int c2 = c + 1, it2 = c2 >> 2, kc2 = c2 & 3;
#pragma unroll
            for (int i = 0; i < 8; ++i) {
                int flat = i * 512 + t, jrow = flat >> 4, f4 = flat & 15;
                pb[i] = *(const float4*)(s2b + (size_t)(it2 * 256 + jrow) * D + kc2 * 64 + f4 * 4);
            }
        }
        __syncthreads();

#pragma unroll
        for (int ks = 0; ks < 2; ++ks) {
            const int kA = kc * 64 + ks * 32 + q * 8;
            bf16x8 ah[2], al8[2];
#pragma unroll
            for (int rt = 0; rt < 2; ++rt) {
                int off = (rh * 32 + rt * 16 + ln) * FB_AST + kA;
                ah[rt]  = *(const bf16x8*)(&Ah[off]);
                al8[rt] = *(const bf16x8*)(&Al[off]);
            }
#pragma unroll
            for (int jt = 0; jt < 4; ++jt) {
                int boff = (jq * 64 + jt * 16 + ln) * FB_BST + ks * 32 + q * 8;
                bf16x8 bh = *(const bf16x8*)(&Bh[boff]);
                bf16x8 bl = *(const bf16x8*)(&Bl[boff]);
#pragma unroll
                for (int rt = 0; rt < 2; ++rt) {
                    acc[rt][jt] = __builtin_amdgcn_mfma_f32_16x16x32_bf16(ah[rt],  bh, acc[rt][jt], 0, 0, 0);
                    acc[rt][jt] = __builtin_amdgcn_mfma_f32_16x16x32_bf16(ah[rt],  bl, acc[rt][jt], 0, 0, 0);
                    acc[rt][jt] = __builtin_amdgcn_mfma_f32_16x16x32_bf16(al8[rt], bh, acc[rt][jt], 0, 0, 0);
                }
            }
        }

        if (kc == 3) {
#pragma unroll
            for (int rt = 0; rt < 2; ++rt)
#pragma unroll
                for (int jt = 0; jt < 4; ++jt)
#pragma unroll
                    for (int r = 0; r < 4; ++r) {
                        float val = acc[rt][jt][r];
                        int j = iter * 256 + jq * 64 + jt * 16 + ln;
                        if (val > v1[rt][r]) { v2[rt][r] = v1[rt][r]; v1[rt][r] = val; i1[rt][r] = j; }
                        else if (val > v2[rt][r]) v2[rt][r] = val;
                    }
        }
    }

#pragma unroll
    for (int rt = 0; rt < 2; ++rt)
#pragma unroll
        for (int r = 0; r < 4; ++r) {
            float a1 = v1[rt][r], a2 = v2[rt][r]; int ai = i1[rt][r];
#pragma unroll
            for (int off = 1; off < 16; off <<= 1) {
                float b1 = __shfl_xor(a1, off);
                int   bi = __shfl_xor(ai, off);
                float b2 = __shfl_xor(a2, off);
                if (b1 > a1 || (b1 == a1 && bi < ai)) { a2 = fmaxf(a1, b2); a1 = b1; ai = bi; }
                else                                   { a2 = fmaxf(b1, a2); }
            }
            if (ln == 0) {
                int row = rh * 32 + rt * 16 + q * 4 + r;
                cv1[row][jq] = a1; cv2[row][jq] = a2; ci1[row][jq] = ai;
            }
        }
    __syncthreads();

    if (t < 64) {
        float V1 = cv1[t][0], V2 = cv2[t][0]; int I = ci1[t][0];
#pragma unroll
        for (int h = 1; h < 4; ++h) {
            float c1 = cv1[t][h], c2 = cv2[t][h]; int ci = ci1[t][h];
            if (c1 > V1 || (c1 == V1 && ci < I)) { V2 = fmaxf(V1, c2); V1 = c1; I = ci; }
            else                                  { V2 = fmaxf(V2, c1); }
        }
        idx_s[t] = I;
        if (qcap > 0 && (V1 - V2) < MARGIN) {
            int pos = atomicAdd(qcount, 1);
            if (pos < qcap) queue[pos] = b * T1 + r0 + t;
        }
    }
    __syncthreads();

    float* ub = u + ((size_t)b * T1 + r0) * D;
#pragma unroll
    for (int i = 0; i < 8; ++i) {
        int flat = i * 512 + t, row = flat >> 6, f4 = flat & 63;
        float4 v = *(const float4*)(s2b + (size_t)idx_s[row] * D + f4 * 4);
        *(float4*)(ub + (size_t)row * D + f4 * 4) = v;
    }
    float* ohb = oh + ((size_t)b * T1 + r0) * T2;
#pragma unroll 4
    for (int i = 0; i < 64; ++i) {
        int flat = i * 512 + t, row = flat >> 9, f4 = flat & 511;
        int base = f4 * 4, id = idx_s[row];
        float4 vv;
        vv.x = (base     == id) ? 1.f : 0.f;
        vv.y = (base + 1 == id) ? 1.f : 0.f;
        vv.z = (base + 2 == id) ? 1.f : 0.f;
        vv.w = (base + 3 == id) ? 1.f : 0.f;
        *(float4*)(ohb + (size_t)row * T2 + base) = vv;
    }
}

extern "C" void kernel_launch(void* const* d_in, const int* in_sizes, int n_in,
                              void* d_out, int out_size, void* d_ws, size_t ws_size,
                              hipStream_t stream)
{
    const float* s1 = (const float*)d_in[0];
    const float* s2 = (const float*)d_in[1];
    float* u  = (float*)d_out;                       // [8,2048,256]
    float* oh = u + (size_t)BB * T1 * D;             // [8,2048,2048]
    char* ws = (char*)d_ws;

    if (ws_size >= WS_NEEDED) {
        int*      qc    = (int*)(ws + OFF_QC);
        int*      queue = (int*)(ws + OFF_QUEUE);
        ushort_t* s1p   = (ushort_t*)(ws + OFF_S1P);
        ushort_t* s2p   = (ushort_t*)(ws + OFF_S2P);
        hipMemsetAsync(ws + OFF_QC, 0, 16, stream);
        k_convert<<<dim3(1024), dim3(256), 0, stream>>>(s1, s2, s1p, s2p);
        k_score_fused<<<dim3(256), dim3(512), 0, stream>>>(s1p, s2p, s2, u, oh, qc, queue);
        k_fixup<<<dim3(128), dim3(256), 0, stream>>>(s1, s2, u, oh, qc, queue, 16384);
    } else {
        int  qcap   = 0;
        int* qcount = nullptr;
        int* queue  = nullptr;
        if (ws_size >= 256) {
            qcount = (int*)d_ws;
            queue  = (int*)d_ws + 4;
            size_t cap = (ws_size - 16) / sizeof(int);
            qcap = (int)(cap > (size_t)(BB * T1) ? (size_t)(BB * T1) : cap);
            hipMemsetAsync(d_ws, 0, 16, stream);
        }
        k_score_fb<<<dim3(BB * (T1 / 64)), dim3(512), 0, stream>>>(
            s1, s2, u, oh, qcount, queue, qcap);
        if (qcap > 0)
            k_fixup<<<dim3(64), dim3(256), 0, stream>>>(
                s1, s2, u, oh, qcount, queue, qcap);
    }
}